// Round 1
// baseline (1588.046 us; speedup 1.0000x reference)
//
#include <hip/hip_runtime.h>
#include <math.h>

#define HH 48
#define WW 48
#define HW 2304
#define BB 4
#define CC 256

// ---------------- corr GEMM: corr[b][q][k] = sum_c f1[b][c][q]*f2[b][c][k] / 16 ----
__global__ __launch_bounds__(256) void corr_gemm_k(const float* __restrict__ f1,
                                                   const float* __restrict__ f2,
                                                   float* __restrict__ corr) {
  int b = blockIdx.z;
  int q0 = blockIdx.y * 64, k0 = blockIdx.x * 64;
  __shared__ float As[16][64];
  __shared__ float Bs[16][64];
  int tid = threadIdx.x;
  int tx = tid & 15, ty = tid >> 4;
  int lc = tid >> 6, lq = tid & 63;
  const float* f1b = f1 + (size_t)b * CC * HW;
  const float* f2b = f2 + (size_t)b * CC * HW;
  float acc[4][4] = {};
  for (int c0 = 0; c0 < CC; c0 += 16) {
#pragma unroll
    for (int j = 0; j < 4; ++j) {
      int c = lc + j * 4;
      As[c][lq] = f1b[(size_t)(c0 + c) * HW + q0 + lq];
      Bs[c][lq] = f2b[(size_t)(c0 + c) * HW + k0 + lq];
    }
    __syncthreads();
#pragma unroll
    for (int c = 0; c < 16; ++c) {
      float4 a4 = *(const float4*)&As[c][ty * 4];
      float4 b4 = *(const float4*)&Bs[c][tx * 4];
      float av[4] = {a4.x, a4.y, a4.z, a4.w};
      float bv[4] = {b4.x, b4.y, b4.z, b4.w};
#pragma unroll
      for (int i = 0; i < 4; ++i)
#pragma unroll
        for (int j = 0; j < 4; ++j) acc[i][j] += av[i] * bv[j];
    }
    __syncthreads();
  }
  float* outp = corr + ((size_t)b * HW + q0) * HW + k0;
#pragma unroll
  for (int i = 0; i < 4; ++i) {
    float4 r = make_float4(acc[i][0] * 0.0625f, acc[i][1] * 0.0625f,
                           acc[i][2] * 0.0625f, acc[i][3] * 0.0625f);
    *(float4*)&outp[(size_t)(ty * 4 + i) * HW + tx * 4] = r;
  }
}

// ---------------- 81-tap bilinear correlation lookup ----------------
// RAFT quirk: px offset uses d[t/9], py offset uses d[t%9].
__global__ __launch_bounds__(256) void corr_lookup_k(const float* __restrict__ corr,
                                                     const float* __restrict__ flow,
                                                     float* __restrict__ cf) {
  int g = blockIdx.x * 256 + threadIdx.x;  // ((b*81+t)*HW+p)
  int p = g % HW;
  int t = (g / HW) % 81;
  int b = g / (81 * HW);
  int y = p / WW, x = p % WW;
  float fx = flow[((size_t)b * 2 + 0) * HW + p];
  float fy = flow[((size_t)b * 2 + 1) * HW + p];
  float px = (float)x + fx + (float)(t / 9 - 4);
  float py = (float)y + fy + (float)(t % 9 - 4);
  const float* row = corr + ((size_t)b * HW + p) * HW;
  float x0f = floorf(px), y0f = floorf(py);
  int x0 = (int)x0f, y0 = (int)y0f;
  float wx = px - x0f, wy = py - y0f;
  float acc = 0.f;
  if ((unsigned)x0 < WW && (unsigned)y0 < HH) acc += row[y0 * WW + x0] * (1.f - wx) * (1.f - wy);
  if ((unsigned)(x0 + 1) < WW && (unsigned)y0 < HH) acc += row[y0 * WW + x0 + 1] * wx * (1.f - wy);
  if ((unsigned)x0 < WW && (unsigned)(y0 + 1) < HH) acc += row[(y0 + 1) * WW + x0] * (1.f - wx) * wy;
  if ((unsigned)(x0 + 1) < WW && (unsigned)(y0 + 1) < HH) acc += row[(y0 + 1) * WW + x0 + 1] * wx * wy;
  cf[g] = acc;
}

// ---------------- direct conv, 4 out-channels per thread ----------------
template <int KS, int PAD, bool RELU>
__global__ __launch_bounds__(256) void conv_direct_k(const float* __restrict__ in,
                                                     const float* __restrict__ wt,
                                                     const float* __restrict__ bias,
                                                     float* __restrict__ out, int Cin,
                                                     int Cout, int ostride, int ooff) {
  int b = blockIdx.z;
  int o0 = blockIdx.y * 4;
  int p = blockIdx.x * 256 + threadIdx.x;
  int y = p / WW, x = p % WW;
  int oi[4];
  float acc[4];
#pragma unroll
  for (int j = 0; j < 4; ++j) {
    oi[j] = min(o0 + j, Cout - 1);
    acc[j] = bias[oi[j]];
  }
  const float* inb = in + (size_t)b * Cin * HW;
  for (int i = 0; i < Cin; ++i) {
    const float* ip = inb + (size_t)i * HW;
    const float* wp0 = wt + ((size_t)oi[0] * Cin + i) * KS * KS;
    const float* wp1 = wt + ((size_t)oi[1] * Cin + i) * KS * KS;
    const float* wp2 = wt + ((size_t)oi[2] * Cin + i) * KS * KS;
    const float* wp3 = wt + ((size_t)oi[3] * Cin + i) * KS * KS;
#pragma unroll
    for (int ky = 0; ky < KS; ++ky) {
      int yy = y + ky - PAD;
      bool yok = (unsigned)yy < (unsigned)HH;
#pragma unroll
      for (int kx = 0; kx < KS; ++kx) {
        int xx = x + kx - PAD;
        float v = (yok && (unsigned)xx < (unsigned)WW) ? ip[yy * WW + xx] : 0.f;
        int wi = ky * KS + kx;
        acc[0] += v * wp0[wi];
        acc[1] += v * wp1[wi];
        acc[2] += v * wp2[wi];
        acc[3] += v * wp3[wi];
      }
    }
  }
#pragma unroll
  for (int j = 0; j < 4; ++j) {
    int o = o0 + j;
    if (o < Cout) {
      float r = RELU ? fmaxf(acc[j], 0.f) : acc[j];
      out[((size_t)b * ostride + ooff + o) * HW + p] = r;
    }
  }
}

// ---------------- copy flow into mf channels 126,127 ----------------
__global__ void copy_flow_k(const float* __restrict__ flow, float* __restrict__ mf) {
  int g = blockIdx.x * 256 + threadIdx.x;  // B*2*HW
  int p = g % HW;
  int c = (g / HW) % 2;
  int b = g / (2 * HW);
  mf[((size_t)b * 128 + 126 + c) * HW + p] = flow[g];
}

// ---------------- srcT (transpose of fmap1) and q = src + sine pos embed ----------------
__global__ __launch_bounds__(256) void pos_q_k(const float* __restrict__ fmap1,
                                               float* __restrict__ srcT,
                                               float* __restrict__ q) {
  int g = blockIdx.x * 256 + threadIdx.x;  // n*256+c
  int c = g & 255;
  int n = g >> 8;
  int b = n / HW;
  int p = n % HW;
  int y = p / WW, x = p % WW;
  float s = fmap1[((size_t)b * CC + c) * HW + p];
  int axis = c >> 7;  // 0 => y channels, 1 => x channels
  int cc = c & 127;
  int m = cc >> 1;
  const float TWO_PI = 6.283185307179586f;
  float coord = (axis ? ((float)x + 0.5f) : ((float)y + 0.5f)) * (TWO_PI / (48.f + 1e-6f));
  float t = exp2f((float)m * (13.287712379549449f / 64.f));  // 10000^(m/64)
  float a = coord / t;
  float pv = (cc & 1) ? cosf(a) : sinf(a);
  srcT[g] = s;
  q[g] = s + pv;
}

// ---------------- generic linear: out[n][o] = A[n][:] . Wt[o][:] + bias[o] ----------------
template <bool RELU>
__global__ __launch_bounds__(256) void linear_k(const float* __restrict__ A,
                                                const float* __restrict__ Wt,
                                                const float* __restrict__ bias,
                                                float* __restrict__ out, int K, int O) {
  int n0 = blockIdx.y * 64, o0 = blockIdx.x * 64;
  __shared__ float As[16][64];
  __shared__ float Ws[16][64];
  int tid = threadIdx.x;
  int tx = tid & 15, ty = tid >> 4;
  int lr = tid >> 2, lk = (tid & 3) * 4;
  int wr = min(o0 + lr, O - 1);
  float acc[4][4] = {};
  for (int k0 = 0; k0 < K; k0 += 16) {
    float4 a = *(const float4*)&A[(size_t)(n0 + lr) * K + k0 + lk];
    float4 w = *(const float4*)&Wt[(size_t)wr * K + k0 + lk];
    As[lk + 0][lr] = a.x;
    As[lk + 1][lr] = a.y;
    As[lk + 2][lr] = a.z;
    As[lk + 3][lr] = a.w;
    Ws[lk + 0][lr] = w.x;
    Ws[lk + 1][lr] = w.y;
    Ws[lk + 2][lr] = w.z;
    Ws[lk + 3][lr] = w.w;
    __syncthreads();
#pragma unroll
    for (int k = 0; k < 16; ++k) {
      float4 a4 = *(const float4*)&As[k][ty * 4];
      float4 b4 = *(const float4*)&Ws[k][tx * 4];
      float av[4] = {a4.x, a4.y, a4.z, a4.w};
      float bv[4] = {b4.x, b4.y, b4.z, b4.w};
#pragma unroll
      for (int i = 0; i < 4; ++i)
#pragma unroll
        for (int j = 0; j < 4; ++j) acc[i][j] += av[i] * bv[j];
    }
    __syncthreads();
  }
#pragma unroll
  for (int i = 0; i < 4; ++i) {
    int n = n0 + ty * 4 + i;
#pragma unroll
    for (int j = 0; j < 4; ++j) {
      int o = o0 + tx * 4 + j;
      if (o < O) {
        float v = acc[i][j] + bias[o];
        if (RELU) v = fmaxf(v, 0.f);
        out[(size_t)n * O + o] = v;
      }
    }
  }
}

// ---------------- softmax over groups of 4 (attention weights) ----------------
__global__ void softmax4_k(float* aw) {
  int g = blockIdx.x * 256 + threadIdx.x;  // N*8
  float* a = aw + (size_t)g * 4;
  float v0 = a[0], v1 = a[1], v2 = a[2], v3 = a[3];
  float m = fmaxf(fmaxf(v0, v1), fmaxf(v2, v3));
  float e0 = expf(v0 - m), e1 = expf(v1 - m), e2 = expf(v2 - m), e3 = expf(v3 - m);
  float inv = 1.f / (e0 + e1 + e2 + e3);
  a[0] = e0 * inv;
  a[1] = e1 * inv;
  a[2] = e2 * inv;
  a[3] = e3 * inv;
}

// ---------------- deformable sampling + weighted sum over points ----------------
__global__ __launch_bounds__(256) void deform_k(const float* __restrict__ val,
                                                const float* __restrict__ off,
                                                const float* __restrict__ aw,
                                                float* __restrict__ attn) {
  int g = blockIdx.x * 256 + threadIdx.x;  // (n*8+h)*32+d
  int d = g & 31;
  int nh = g >> 5;
  int h = nh & 7;
  int n = nh >> 3;
  int b = n / HW;
  int p = n % HW;
  int y = p / WW, x = p % WW;
  const float* vb = val + (size_t)b * HW * 256 + h * 32 + d;
  float acc = 0.f;
#pragma unroll
  for (int pt = 0; pt < 4; ++pt) {
    float ox = off[(size_t)n * 64 + h * 8 + pt * 2 + 0];
    float oy = off[(size_t)n * 64 + h * 8 + pt * 2 + 1];
    float w = aw[(size_t)n * 32 + h * 4 + pt];
    float px = (float)x + ox, py = (float)y + oy;  // align_corners=False algebra
    float x0f = floorf(px), y0f = floorf(py);
    int x0 = (int)x0f, y0 = (int)y0f;
    float wx = px - x0f, wy = py - y0f;
    float s = 0.f;
    if ((unsigned)x0 < WW && (unsigned)y0 < HH)
      s += vb[(size_t)(y0 * WW + x0) * 256] * (1.f - wx) * (1.f - wy);
    if ((unsigned)(x0 + 1) < WW && (unsigned)y0 < HH)
      s += vb[(size_t)(y0 * WW + x0 + 1) * 256] * wx * (1.f - wy);
    if ((unsigned)x0 < WW && (unsigned)(y0 + 1) < HH)
      s += vb[(size_t)((y0 + 1) * WW + x0) * 256] * (1.f - wx) * wy;
    if ((unsigned)(x0 + 1) < WW && (unsigned)(y0 + 1) < HH)
      s += vb[(size_t)((y0 + 1) * WW + x0 + 1) * 256] * wx * wy;
    acc += w * s;
  }
  attn[(size_t)n * 256 + h * 32 + d] = acc;
}

// ---------------- fused residual add + LayerNorm over 256 ----------------
__global__ __launch_bounds__(256) void ln_add_k(const float* __restrict__ A,
                                                const float* __restrict__ Bv,
                                                const float* __restrict__ g,
                                                const float* __restrict__ be,
                                                float* __restrict__ out) {
  int n = blockIdx.x;
  int c = threadIdx.x;
  float v = A[(size_t)n * 256 + c] + Bv[(size_t)n * 256 + c];
  float s1 = v, s2 = v * v;
#pragma unroll
  for (int o = 32; o > 0; o >>= 1) {
    s1 += __shfl_down(s1, o);
    s2 += __shfl_down(s2, o);
  }
  __shared__ float r1[4], r2[4], mv[2];
  int wid = c >> 6, lane = c & 63;
  if (lane == 0) {
    r1[wid] = s1;
    r2[wid] = s2;
  }
  __syncthreads();
  if (c == 0) {
    float a = r1[0] + r1[1] + r1[2] + r1[3];
    float q2 = r2[0] + r2[1] + r2[2] + r2[3];
    float mean = a * (1.f / 256.f);
    mv[0] = mean;
    mv[1] = q2 * (1.f / 256.f) - mean * mean;
  }
  __syncthreads();
  float mean = mv[0], var = mv[1];
  out[(size_t)n * 256 + c] = (v - mean) * rsqrtf(var + 1e-5f) * g[c] + be[c];
}

extern "C" void kernel_launch(void* const* d_in, const int* in_sizes, int n_in,
                              void* d_out, int out_size, void* d_ws, size_t ws_size,
                              hipStream_t stream) {
  const float* fmap1 = (const float*)d_in[0];
  const float* fmap2 = (const float*)d_in[1];
  const float* flow = (const float*)d_in[2];
  const float* wc1 = (const float*)d_in[3];
  const float* bc1 = (const float*)d_in[4];
  const float* wc2 = (const float*)d_in[5];
  const float* bc2 = (const float*)d_in[6];
  const float* wf1 = (const float*)d_in[7];
  const float* bf1 = (const float*)d_in[8];
  const float* wf2 = (const float*)d_in[9];
  const float* bf2 = (const float*)d_in[10];
  const float* wcf = (const float*)d_in[11];
  const float* bcf = (const float*)d_in[12];
  const float* wfh1 = (const float*)d_in[13];
  const float* bfh1 = (const float*)d_in[14];
  const float* wfh2 = (const float*)d_in[15];
  const float* bfh2 = (const float*)d_in[16];
  const float* w_off = (const float*)d_in[17];
  const float* b_off = (const float*)d_in[18];
  const float* w_aw = (const float*)d_in[19];
  const float* b_aw = (const float*)d_in[20];
  const float* w_val = (const float*)d_in[21];
  const float* b_val = (const float*)d_in[22];
  const float* w_out = (const float*)d_in[23];
  const float* b_out = (const float*)d_in[24];
  const float* ln1_g = (const float*)d_in[25];
  const float* ln1_b = (const float*)d_in[26];
  const float* w_ff1 = (const float*)d_in[27];
  const float* b_ff1 = (const float*)d_in[28];
  const float* w_ff2 = (const float*)d_in[29];
  const float* b_ff2 = (const float*)d_in[30];
  const float* ln2_g = (const float*)d_in[31];
  const float* ln2_b = (const float*)d_in[32];

  float* ws = (float*)d_ws;
  float* out_src = (float*)d_out;                 // [B,HW,256]
  float* out_df = out_src + (size_t)BB * HW * CC; // [B,2,H,W]

  // Workspace layout (floats). corr region [0, 21233664) reused after lookup.
  const size_t F_CORR = 0;
  const size_t F_CF = 21233664;  // corr_feat [B,81,HW], end = 21980160 (≈88 MB)
  // aliases inside dead corr region (strictly sequential liveness):
  const size_t F_COR1 = 0;         // [B,256,HW]
  const size_t F_CAT = 2359296;    // [B,256,HW] (cor2 ch0-191, flo2 ch192-255)
  const size_t F_FLO1 = 4718592;   // [B,128,HW]
  const size_t F_MF = 5898240;     // [B,128,HW]
  const size_t F_FH1 = 7077888;    // [B,256,HW]
  const size_t F_Q = 9437184;      // [N,256]
  const size_t F_SRCT = 11796480;  // [N,256]
  const size_t F_OFF = 14155776;   // [N,64]
  const size_t F_AW = 14745600;    // [N,32]
  const size_t F_VAL = 15040512;   // [N,256]
  const size_t F_ATTN = 17399808;  // [N,256]
  const size_t F_TMP = 0;          // reuse cor1
  const size_t F_SRC1 = 2359296;   // reuse cat
  const size_t F_FF1 = 4718592;    // [N,1024], reuse flo1..srcT (all dead)
  const size_t F_FF2 = 14155776;   // reuse off/aw/val (dead)

  // 1. correlation volume
  corr_gemm_k<<<dim3(36, 36, 4), 256, 0, stream>>>(fmap1, fmap2, ws + F_CORR);
  // 2. lookup
  corr_lookup_k<<<dim3(2916), 256, 0, stream>>>(ws + F_CORR, flow, ws + F_CF);
  // 3-10. motion encoder + flow head
  conv_direct_k<1, 0, true><<<dim3(9, 64, 4), 256, 0, stream>>>(ws + F_CF, wc1, bc1, ws + F_COR1, 81, 256, 256, 0);
  conv_direct_k<3, 1, true><<<dim3(9, 48, 4), 256, 0, stream>>>(ws + F_COR1, wc2, bc2, ws + F_CAT, 256, 192, 256, 0);
  conv_direct_k<7, 3, true><<<dim3(9, 32, 4), 256, 0, stream>>>(flow, wf1, bf1, ws + F_FLO1, 2, 128, 128, 0);
  conv_direct_k<3, 1, true><<<dim3(9, 16, 4), 256, 0, stream>>>(ws + F_FLO1, wf2, bf2, ws + F_CAT, 128, 64, 256, 192);
  conv_direct_k<3, 1, true><<<dim3(9, 32, 4), 256, 0, stream>>>(ws + F_CAT, wcf, bcf, ws + F_MF, 256, 126, 128, 0);
  copy_flow_k<<<dim3(72), 256, 0, stream>>>(flow, ws + F_MF);
  conv_direct_k<3, 1, true><<<dim3(9, 64, 4), 256, 0, stream>>>(ws + F_MF, wfh1, bfh1, ws + F_FH1, 128, 256, 256, 0);
  conv_direct_k<3, 1, false><<<dim3(9, 1, 4), 256, 0, stream>>>(ws + F_FH1, wfh2, bfh2, out_df, 256, 2, 2, 0);
  // 11. srcT + q (src + pos embed)
  pos_q_k<<<dim3(9216), 256, 0, stream>>>(fmap1, ws + F_SRCT, ws + F_Q);
  // 12-14. projections
  linear_k<false><<<dim3(1, 144), 256, 0, stream>>>(ws + F_Q, w_off, b_off, ws + F_OFF, 256, 64);
  linear_k<false><<<dim3(1, 144), 256, 0, stream>>>(ws + F_Q, w_aw, b_aw, ws + F_AW, 256, 32);
  linear_k<false><<<dim3(4, 144), 256, 0, stream>>>(ws + F_SRCT, w_val, b_val, ws + F_VAL, 256, 256);
  // 15. softmax over NP
  softmax4_k<<<dim3(288), 256, 0, stream>>>(ws + F_AW);
  // 16. deformable sampling
  deform_k<<<dim3(9216), 256, 0, stream>>>(ws + F_VAL, ws + F_OFF, ws + F_AW, ws + F_ATTN);
  // 17. output projection
  linear_k<false><<<dim3(4, 144), 256, 0, stream>>>(ws + F_ATTN, w_out, b_out, ws + F_TMP, 256, 256);
  // 18. LN1(src + attn)
  ln_add_k<<<dim3(9216), 256, 0, stream>>>(ws + F_TMP, ws + F_SRCT, ln1_g, ln1_b, ws + F_SRC1);
  // 19-20. FFN
  linear_k<true><<<dim3(16, 144), 256, 0, stream>>>(ws + F_SRC1, w_ff1, b_ff1, ws + F_FF1, 256, 1024);
  linear_k<false><<<dim3(4, 144), 256, 0, stream>>>(ws + F_FF1, w_ff2, b_ff2, ws + F_FF2, 1024, 256);
  // 21. LN2(src1 + ff) -> final src output
  ln_add_k<<<dim3(9216), 256, 0, stream>>>(ws + F_FF2, ws + F_SRC1, ln2_g, ln2_b, out_src);

  (void)in_sizes; (void)n_in; (void)out_size; (void)ws_size;
}

// Round 3
// 743.490 us; speedup vs baseline: 2.1359x; 2.1359x over previous
//
#include <hip/hip_runtime.h>
#include <hip/hip_bf16.h>
#include <math.h>

#define HH 48
#define WW 48
#define HW 2304
#define BB 4
#define CC 256

typedef __hip_bfloat16 bf16;
typedef __attribute__((ext_vector_type(8))) short s8v;
typedef __attribute__((ext_vector_type(4))) float f4v;

__device__ inline float bf2f(short u) {
  unsigned v = ((unsigned)(unsigned short)u) << 16;
  return __builtin_bit_cast(float, v);
}

// ---------------- corr GEMM: corr[b][q][k] = sum_c f1[b][c][q]*f2[b][c][k] / 16 ----
__global__ __launch_bounds__(256) void corr_gemm_k(const float* __restrict__ f1,
                                                   const float* __restrict__ f2,
                                                   float* __restrict__ corr) {
  int b = blockIdx.z;
  int q0 = blockIdx.y * 64, k0 = blockIdx.x * 64;
  __shared__ float As[16][64];
  __shared__ float Bs[16][64];
  int tid = threadIdx.x;
  int tx = tid & 15, ty = tid >> 4;
  int lc = tid >> 6, lq = tid & 63;
  const float* f1b = f1 + (size_t)b * CC * HW;
  const float* f2b = f2 + (size_t)b * CC * HW;
  float acc[4][4] = {};
  for (int c0 = 0; c0 < CC; c0 += 16) {
#pragma unroll
    for (int j = 0; j < 4; ++j) {
      int c = lc + j * 4;
      As[c][lq] = f1b[(size_t)(c0 + c) * HW + q0 + lq];
      Bs[c][lq] = f2b[(size_t)(c0 + c) * HW + k0 + lq];
    }
    __syncthreads();
#pragma unroll
    for (int c = 0; c < 16; ++c) {
      float4 a4 = *(const float4*)&As[c][ty * 4];
      float4 b4 = *(const float4*)&Bs[c][tx * 4];
      float av[4] = {a4.x, a4.y, a4.z, a4.w};
      float bv[4] = {b4.x, b4.y, b4.z, b4.w};
#pragma unroll
      for (int i = 0; i < 4; ++i)
#pragma unroll
        for (int j = 0; j < 4; ++j) acc[i][j] += av[i] * bv[j];
    }
    __syncthreads();
  }
  float* outp = corr + ((size_t)b * HW + q0) * HW + k0;
#pragma unroll
  for (int i = 0; i < 4; ++i) {
    float4 r = make_float4(acc[i][0] * 0.0625f, acc[i][1] * 0.0625f,
                           acc[i][2] * 0.0625f, acc[i][3] * 0.0625f);
    *(float4*)&outp[(size_t)(ty * 4 + i) * HW + tx * 4] = r;
  }
}

// ---------------- 81-tap bilinear correlation lookup -> channels-last bf16 [n][96] ----
// RAFT quirk: px offset uses d[t/9], py offset uses d[t%9].
__global__ __launch_bounds__(256) void corr_lookup_k(const float* __restrict__ corr,
                                                     const float* __restrict__ flow,
                                                     bf16* __restrict__ cf) {
  int g = blockIdx.x * 256 + threadIdx.x;  // n*96 + t
  int t = g % 96;
  int n = g / 96;
  if (t >= 81) { cf[g] = (bf16)0.f; return; }
  int b = n / HW;
  int p = n % HW;
  int y = p / WW, x = p % WW;
  float fx = flow[((size_t)b * 2 + 0) * HW + p];
  float fy = flow[((size_t)b * 2 + 1) * HW + p];
  float px = (float)x + fx + (float)(t / 9 - 4);
  float py = (float)y + fy + (float)(t % 9 - 4);
  const float* row = corr + (size_t)n * HW;
  float x0f = floorf(px), y0f = floorf(py);
  int x0 = (int)x0f, y0 = (int)y0f;
  float wx = px - x0f, wy = py - y0f;
  float acc = 0.f;
  if ((unsigned)x0 < WW && (unsigned)y0 < HH) acc += row[y0 * WW + x0] * (1.f - wx) * (1.f - wy);
  if ((unsigned)(x0 + 1) < WW && (unsigned)y0 < HH) acc += row[y0 * WW + x0 + 1] * wx * (1.f - wy);
  if ((unsigned)x0 < WW && (unsigned)(y0 + 1) < HH) acc += row[(y0 + 1) * WW + x0] * (1.f - wx) * wy;
  if ((unsigned)(x0 + 1) < WW && (unsigned)(y0 + 1) < HH) acc += row[(y0 + 1) * WW + x0 + 1] * wx * wy;
  cf[g] = (bf16)acc;
}

// ---------------- weight convert: w[o][cin][ky][kx] fp32 -> wk[t][o][kp] bf16 (zero pad) ----
__global__ void wt_conv_k(const float* __restrict__ w, bf16* __restrict__ wk,
                          int Cout, int Cin, int KP, int KS) {
  int idx = blockIdx.x * 256 + threadIdx.x;
  int total = KS * KS * Cout * KP;
  if (idx >= total) return;
  int c = idx % KP;
  int o = (idx / KP) % Cout;
  int t = idx / (KP * Cout);
  float v = (c < Cin) ? w[((size_t)o * Cin + c) * (KS * KS) + t] : 0.f;
  wk[idx] = (bf16)v;
}

// ---------------- implicit-GEMM MFMA conv (3x3 pad1 or 1x1) ----------------
// in: [B*HW][KP] bf16 channels-last (zero-padded K); wt: [TAPS][Cout][KP] bf16;
// out: [B*HW][OStride] bf16, cols OOff..OOff+Cout-1. 64x64 tile, 4 waves of 32x32.
template <int TAPS, int KP>
__global__ __launch_bounds__(256) void conv_mfma_k(const bf16* __restrict__ in,
                                                   const bf16* __restrict__ wt,
                                                   const float* __restrict__ bias,
                                                   bf16* __restrict__ out, int Cout,
                                                   int OStride, int OOff, int relu) {
  int b = blockIdx.z;
  int m0 = blockIdx.y * 64;
  int n0 = blockIdx.x * 64;
  __shared__ short As[64][32];
  __shared__ short Bs[64][32];
  int tid = threadIdx.x;
  int srow = tid >> 2;   // staging row 0..63
  int sk8 = tid & 3;     // k8 slot
  int dstk = (sk8 ^ (srow & 3)) * 8;  // XOR-swizzled LDS col
  int q = m0 + srow;
  int y = q / WW, x = q - y * WW;
  int wave = tid >> 6;
  int lane = tid & 63;
  int wm = (wave >> 1) * 32;
  int wn = (wave & 1) * 32;
  int fl = lane & 15;
  int fk8 = lane >> 4;
  f4v acc[2][2] = {};
  const bf16* inb = in + (size_t)b * HW * KP;
  int wo = n0 + srow;
  bool wvalid = wo < Cout;
  for (int t = 0; t < TAPS; ++t) {
    int ky = (TAPS == 9) ? t / 3 : 0;
    int kx = (TAPS == 9) ? t - ky * 3 : 0;
    int yy = (TAPS == 9) ? (y + ky - 1) : y;
    int xx = (TAPS == 9) ? (x + kx - 1) : x;
    bool valid = ((unsigned)yy < (unsigned)HH) & ((unsigned)xx < (unsigned)WW);
    const bf16* srcrow = inb + (size_t)(yy * WW + xx) * KP;
    const bf16* wrow = wt + ((size_t)t * Cout + (wvalid ? wo : 0)) * KP;
#pragma unroll
    for (int c0 = 0; c0 < KP; c0 += 32) {
      uint4 av = {0u, 0u, 0u, 0u};
      if (valid) av = *(const uint4*)(srcrow + c0 + sk8 * 8);
      uint4 bv = {0u, 0u, 0u, 0u};
      if (wvalid) bv = *(const uint4*)(wrow + c0 + sk8 * 8);
      *(uint4*)&As[srow][dstk] = av;
      *(uint4*)&Bs[srow][dstk] = bv;
      __syncthreads();
      s8v af[2], bfr[2];
#pragma unroll
      for (int i = 0; i < 2; ++i) {
        int ar = wm + i * 16 + fl;
        af[i] = *(const s8v*)&As[ar][(fk8 ^ (ar & 3)) * 8];
        int br = wn + i * 16 + fl;
        bfr[i] = *(const s8v*)&Bs[br][(fk8 ^ (br & 3)) * 8];
      }
#pragma unroll
      for (int i = 0; i < 2; ++i)
#pragma unroll
        for (int j = 0; j < 2; ++j)
          acc[i][j] = __builtin_amdgcn_mfma_f32_16x16x32_bf16(af[i], bfr[j], acc[i][j], 0, 0, 0);
      __syncthreads();
    }
  }
  // C/D layout: col = lane&15, row = (lane>>4)*4 + r.
  // Store channel o (global, includes n0) at pixel m0+m; outbase carries OOff.
  size_t outbase = ((size_t)b * HW + m0) * OStride + OOff;
#pragma unroll
  for (int j = 0; j < 2; ++j) {
    int o = n0 + wn + j * 16 + fl;
    if (o < Cout) {
      float bsv = bias[o];
#pragma unroll
      for (int i = 0; i < 2; ++i)
#pragma unroll
        for (int r = 0; r < 4; ++r) {
          int m = wm + i * 16 + fk8 * 4 + r;
          float v = acc[i][j][r] + bsv;
          if (relu) v = fmaxf(v, 0.f);
          out[outbase + (size_t)m * OStride + o] = (bf16)v;
        }
    }
  }
}

// ---------------- 7x7 conv, Cin=2, Cout=128, LDS weights, channels-last bf16 out ----
__global__ __launch_bounds__(256) void conv7_k(const float* __restrict__ flow,
                                               const float* __restrict__ wf1,
                                               const float* __restrict__ bf1,
                                               bf16* __restrict__ out) {
  __shared__ float wl[49 * 2 * 128];
  int tid = threadIdx.x;
  for (int i = tid; i < 12544; i += 256) {
    int o_ = i & 127;
    int c_ = (i >> 7) & 1;
    int k_ = i >> 8;
    wl[i] = wf1[((size_t)o_ * 2 + c_) * 49 + k_];
  }
  __syncthreads();
  int pix = blockIdx.x * 2 + (tid >> 7);  // over B*HW
  int o = tid & 127;
  int b = pix / HW;
  int p = pix % HW;
  int y = p / WW, x = p % WW;
  const float* f0 = flow + (size_t)b * 2 * HW;
  float acc = bf1[o];
  for (int ky = 0; ky < 7; ++ky) {
    int yy = y + ky - 3;
    if ((unsigned)yy >= (unsigned)HH) continue;
    for (int kx = 0; kx < 7; ++kx) {
      int xx = x + kx - 3;
      if ((unsigned)xx >= (unsigned)WW) continue;
      int sp = yy * WW + xx;
      float v0 = f0[sp];
      float v1 = f0[HW + sp];
      int k = ky * 7 + kx;
      acc += v0 * wl[(k * 2 + 0) * 128 + o] + v1 * wl[(k * 2 + 1) * 128 + o];
    }
  }
  out[(size_t)pix * 128 + o] = (bf16)fmaxf(acc, 0.f);
}

// ---------------- final 3x3 conv 256->2, reads bf16 channels-last ----------------
__global__ __launch_bounds__(256) void convfh2_k(const bf16* __restrict__ fh1,
                                                 const float* __restrict__ w,
                                                 const float* __restrict__ bias,
                                                 float* __restrict__ out) {
  int p = blockIdx.x * 256 + threadIdx.x;  // over B*HW
  int b = p / HW;
  int q = p % HW;
  int y = q / WW, x = q % WW;
  float a0 = bias[0], a1 = bias[1];
  for (int ky = 0; ky < 3; ++ky) {
    int yy = y + ky - 1;
    if ((unsigned)yy >= (unsigned)HH) continue;
    for (int kx = 0; kx < 3; ++kx) {
      int xx = x + kx - 1;
      if ((unsigned)xx >= (unsigned)WW) continue;
      const s8v* row = (const s8v*)(fh1 + ((size_t)b * HW + yy * WW + xx) * 256);
      int t = ky * 3 + kx;
      for (int c8 = 0; c8 < 32; ++c8) {
        s8v v = row[c8];
#pragma unroll
        for (int j = 0; j < 8; ++j) {
          float fv = bf2f(v[j]);
          int c = c8 * 8 + j;
          a0 += fv * w[(size_t)(0 * 256 + c) * 9 + t];
          a1 += fv * w[(size_t)(1 * 256 + c) * 9 + t];
        }
      }
    }
  }
  out[(size_t)b * 2 * HW + q] = a0;
  out[((size_t)b * 2 + 1) * HW + q] = a1;
}

// ---------------- copy flow into mf_cat cols 126,127 (bf16) ----------------
__global__ void copy_flow_k(const float* __restrict__ flow, bf16* __restrict__ mf) {
  int g = blockIdx.x * 256 + threadIdx.x;  // B*2*HW
  int p = g % HW;
  int c = (g / HW) % 2;
  int b = g / (2 * HW);
  mf[((size_t)b * HW + p) * 128 + 126 + c] = (bf16)flow[g];
}

// ---------------- srcT (transpose of fmap1) and q = src + sine pos embed ----------------
__global__ __launch_bounds__(256) void pos_q_k(const float* __restrict__ fmap1,
                                               float* __restrict__ srcT,
                                               float* __restrict__ q) {
  int g = blockIdx.x * 256 + threadIdx.x;  // n*256+c
  int c = g & 255;
  int n = g >> 8;
  int b = n / HW;
  int p = n % HW;
  int y = p / WW, x = p % WW;
  float s = fmap1[((size_t)b * CC + c) * HW + p];
  int axis = c >> 7;
  int cc = c & 127;
  int m = cc >> 1;
  const float TWO_PI = 6.283185307179586f;
  float coord = (axis ? ((float)x + 0.5f) : ((float)y + 0.5f)) * (TWO_PI / (48.f + 1e-6f));
  float t = exp2f((float)m * (13.287712379549449f / 64.f));
  float a = coord / t;
  float pv = (cc & 1) ? cosf(a) : sinf(a);
  srcT[g] = s;
  q[g] = s + pv;
}

// ---------------- generic fp32 linear ----------------
template <bool RELU>
__global__ __launch_bounds__(256) void linear_k(const float* __restrict__ A,
                                                const float* __restrict__ Wt,
                                                const float* __restrict__ bias,
                                                float* __restrict__ out, int K, int O) {
  int n0 = blockIdx.y * 64, o0 = blockIdx.x * 64;
  __shared__ float As[16][64];
  __shared__ float Ws[16][64];
  int tid = threadIdx.x;
  int tx = tid & 15, ty = tid >> 4;
  int lr = tid >> 2, lk = (tid & 3) * 4;
  int wr = min(o0 + lr, O - 1);
  float acc[4][4] = {};
  for (int k0 = 0; k0 < K; k0 += 16) {
    float4 a = *(const float4*)&A[(size_t)(n0 + lr) * K + k0 + lk];
    float4 w = *(const float4*)&Wt[(size_t)wr * K + k0 + lk];
    As[lk + 0][lr] = a.x;
    As[lk + 1][lr] = a.y;
    As[lk + 2][lr] = a.z;
    As[lk + 3][lr] = a.w;
    Ws[lk + 0][lr] = w.x;
    Ws[lk + 1][lr] = w.y;
    Ws[lk + 2][lr] = w.z;
    Ws[lk + 3][lr] = w.w;
    __syncthreads();
#pragma unroll
    for (int k = 0; k < 16; ++k) {
      float4 a4 = *(const float4*)&As[k][ty * 4];
      float4 b4 = *(const float4*)&Ws[k][tx * 4];
      float av[4] = {a4.x, a4.y, a4.z, a4.w};
      float bv[4] = {b4.x, b4.y, b4.z, b4.w};
#pragma unroll
      for (int i = 0; i < 4; ++i)
#pragma unroll
        for (int j = 0; j < 4; ++j) acc[i][j] += av[i] * bv[j];
    }
    __syncthreads();
  }
#pragma unroll
  for (int i = 0; i < 4; ++i) {
    int n = n0 + ty * 4 + i;
#pragma unroll
    for (int j = 0; j < 4; ++j) {
      int o = o0 + tx * 4 + j;
      if (o < O) {
        float v = acc[i][j] + bias[o];
        if (RELU) v = fmaxf(v, 0.f);
        out[(size_t)n * O + o] = v;
      }
    }
  }
}

// ---------------- softmax over groups of 4 ----------------
__global__ void softmax4_k(float* aw) {
  int g = blockIdx.x * 256 + threadIdx.x;
  float* a = aw + (size_t)g * 4;
  float v0 = a[0], v1 = a[1], v2 = a[2], v3 = a[3];
  float m = fmaxf(fmaxf(v0, v1), fmaxf(v2, v3));
  float e0 = expf(v0 - m), e1 = expf(v1 - m), e2 = expf(v2 - m), e3 = expf(v3 - m);
  float inv = 1.f / (e0 + e1 + e2 + e3);
  a[0] = e0 * inv;
  a[1] = e1 * inv;
  a[2] = e2 * inv;
  a[3] = e3 * inv;
}

// ---------------- deformable sampling ----------------
__global__ __launch_bounds__(256) void deform_k(const float* __restrict__ val,
                                                const float* __restrict__ off,
                                                const float* __restrict__ aw,
                                                float* __restrict__ attn) {
  int g = blockIdx.x * 256 + threadIdx.x;
  int d = g & 31;
  int nh = g >> 5;
  int h = nh & 7;
  int n = nh >> 3;
  int b = n / HW;
  int p = n % HW;
  int y = p / WW, x = p % WW;
  const float* vb = val + (size_t)b * HW * 256 + h * 32 + d;
  float acc = 0.f;
#pragma unroll
  for (int pt = 0; pt < 4; ++pt) {
    float ox = off[(size_t)n * 64 + h * 8 + pt * 2 + 0];
    float oy = off[(size_t)n * 64 + h * 8 + pt * 2 + 1];
    float w = aw[(size_t)n * 32 + h * 4 + pt];
    float px = (float)x + ox, py = (float)y + oy;
    float x0f = floorf(px), y0f = floorf(py);
    int x0 = (int)x0f, y0 = (int)y0f;
    float wx = px - x0f, wy = py - y0f;
    float s = 0.f;
    if ((unsigned)x0 < WW && (unsigned)y0 < HH)
      s += vb[(size_t)(y0 * WW + x0) * 256] * (1.f - wx) * (1.f - wy);
    if ((unsigned)(x0 + 1) < WW && (unsigned)y0 < HH)
      s += vb[(size_t)(y0 * WW + x0 + 1) * 256] * wx * (1.f - wy);
    if ((unsigned)x0 < WW && (unsigned)(y0 + 1) < HH)
      s += vb[(size_t)((y0 + 1) * WW + x0) * 256] * (1.f - wx) * wy;
    if ((unsigned)(x0 + 1) < WW && (unsigned)(y0 + 1) < HH)
      s += vb[(size_t)((y0 + 1) * WW + x0 + 1) * 256] * wx * wy;
    acc += w * s;
  }
  attn[(size_t)n * 256 + h * 32 + d] = acc;
}

// ---------------- fused residual add + LayerNorm over 256 ----------------
__global__ __launch_bounds__(256) void ln_add_k(const float* __restrict__ A,
                                                const float* __restrict__ Bv,
                                                const float* __restrict__ g,
                                                const float* __restrict__ be,
                                                float* __restrict__ out) {
  int n = blockIdx.x;
  int c = threadIdx.x;
  float v = A[(size_t)n * 256 + c] + Bv[(size_t)n * 256 + c];
  float s1 = v, s2 = v * v;
#pragma unroll
  for (int o = 32; o > 0; o >>= 1) {
    s1 += __shfl_down(s1, o);
    s2 += __shfl_down(s2, o);
  }
  __shared__ float r1[4], r2[4], mv[2];
  int wid = c >> 6, lane = c & 63;
  if (lane == 0) {
    r1[wid] = s1;
    r2[wid] = s2;
  }
  __syncthreads();
  if (c == 0) {
    float a = r1[0] + r1[1] + r1[2] + r1[3];
    float q2 = r2[0] + r2[1] + r2[2] + r2[3];
    float mean = a * (1.f / 256.f);
    mv[0] = mean;
    mv[1] = q2 * (1.f / 256.f) - mean * mean;
  }
  __syncthreads();
  float mean = mv[0], var = mv[1];
  out[(size_t)n * 256 + c] = (v - mean) * rsqrtf(var + 1e-5f) * g[c] + be[c];
}

extern "C" void kernel_launch(void* const* d_in, const int* in_sizes, int n_in,
                              void* d_out, int out_size, void* d_ws, size_t ws_size,
                              hipStream_t stream) {
  const float* fmap1 = (const float*)d_in[0];
  const float* fmap2 = (const float*)d_in[1];
  const float* flow = (const float*)d_in[2];
  const float* wc1 = (const float*)d_in[3];
  const float* bc1 = (const float*)d_in[4];
  const float* wc2 = (const float*)d_in[5];
  const float* bc2 = (const float*)d_in[6];
  const float* wf1 = (const float*)d_in[7];
  const float* bf1 = (const float*)d_in[8];
  const float* wf2 = (const float*)d_in[9];
  const float* bf2 = (const float*)d_in[10];
  const float* wcf = (const float*)d_in[11];
  const float* bcf = (const float*)d_in[12];
  const float* wfh1 = (const float*)d_in[13];
  const float* bfh1 = (const float*)d_in[14];
  const float* wfh2 = (const float*)d_in[15];
  const float* bfh2 = (const float*)d_in[16];
  const float* w_off = (const float*)d_in[17];
  const float* b_off = (const float*)d_in[18];
  const float* w_aw = (const float*)d_in[19];
  const float* b_aw = (const float*)d_in[20];
  const float* w_val = (const float*)d_in[21];
  const float* b_val = (const float*)d_in[22];
  const float* w_out = (const float*)d_in[23];
  const float* b_out = (const float*)d_in[24];
  const float* ln1_g = (const float*)d_in[25];
  const float* ln1_b = (const float*)d_in[26];
  const float* w_ff1 = (const float*)d_in[27];
  const float* b_ff1 = (const float*)d_in[28];
  const float* w_ff2 = (const float*)d_in[29];
  const float* b_ff2 = (const float*)d_in[30];
  const float* ln2_g = (const float*)d_in[31];
  const float* ln2_b = (const float*)d_in[32];

  float* ws = (float*)d_ws;
  float* out_src = (float*)d_out;
  float* out_df = out_src + (size_t)BB * HW * CC;

  // ---- workspace layout (float offsets) ----
  const size_t F_CORR = 0;           // [B,HW,HW] fp32, dead after lookup
  const size_t F_CF = 21233664;      // [n][96] bf16 (442368 fl)
  // aliases inside dead corr region (sequential liveness):
  const size_t F_WK = 0;             // all conv weights bf16 (562944 fl)
  const size_t F_COR1 = 600000;      // [n][256] bf16
  const size_t F_CAT = 1800000;      // [n][256] bf16
  const size_t F_FLO1 = 3000000;     // [n][128] bf16
  const size_t F_MF = 3600000;       // [n][128] bf16
  const size_t F_FH1 = 4200000;      // [n][256] bf16
  const size_t F_Q = 5400000;        // [n][256] fp32
  const size_t F_SRCT = 7800000;     // [n][256] fp32
  const size_t F_OFF = 10200000;     // [n][64] fp32
  const size_t F_AW = 10800000;      // [n][32] fp32
  const size_t F_VAL = 11100000;     // [n][256] fp32
  const size_t F_ATTN = 13500000;    // [n][256] fp32
  const size_t F_TMP = 15900000;     // [n][256] fp32
  const size_t F_SRC1 = 18300000;    // [n][256] fp32
  const size_t F_FF1 = 0;           // [n][1024] fp32 (9437184 fl; everything below dead)
  const size_t F_FF2 = 9600000;     // [n][256] fp32

  bf16* cf = (bf16*)(ws + F_CF);
  bf16* wkbase = (bf16*)(ws + F_WK);
  bf16* wk1 = wkbase + 0;        // [1][256][96]   = 24576
  bf16* wk2 = wkbase + 24576;    // [9][192][256]  = 442368
  bf16* wkf2 = wkbase + 466944;  // [9][64][128]   = 73728
  bf16* wkcf = wkbase + 540672;  // [9][126][256]  = 290304
  bf16* wkfh1 = wkbase + 830976; // [9][256][128]  = 294912
  bf16* cor1 = (bf16*)(ws + F_COR1);
  bf16* cat = (bf16*)(ws + F_CAT);
  bf16* flo1 = (bf16*)(ws + F_FLO1);
  bf16* mf = (bf16*)(ws + F_MF);
  bf16* fh1 = (bf16*)(ws + F_FH1);

  // 1. correlation volume
  corr_gemm_k<<<dim3(36, 36, 4), 256, 0, stream>>>(fmap1, fmap2, ws + F_CORR);
  // 2. lookup -> cf bf16 [n][96]
  corr_lookup_k<<<dim3(3456), 256, 0, stream>>>(ws + F_CORR, flow, cf);
  // 3. weight conversions (corr dead now)
  wt_conv_k<<<dim3(96), 256, 0, stream>>>(wc1, wk1, 256, 81, 96, 1);
  wt_conv_k<<<dim3(1728), 256, 0, stream>>>(wc2, wk2, 192, 256, 256, 3);
  wt_conv_k<<<dim3(288), 256, 0, stream>>>(wf2, wkf2, 64, 128, 128, 3);
  wt_conv_k<<<dim3(1134), 256, 0, stream>>>(wcf, wkcf, 126, 256, 256, 3);
  wt_conv_k<<<dim3(1152), 256, 0, stream>>>(wfh1, wkfh1, 256, 128, 128, 3);
  // 4. motion encoder + flow head (MFMA implicit GEMM)
  conv_mfma_k<1, 96><<<dim3(4, 36, 4), 256, 0, stream>>>(cf, wk1, bc1, cor1, 256, 256, 0, 1);
  conv_mfma_k<9, 256><<<dim3(3, 36, 4), 256, 0, stream>>>(cor1, wk2, bc2, cat, 192, 256, 0, 1);
  conv7_k<<<dim3(4608), 256, 0, stream>>>(flow, wf1, bf1, flo1);
  conv_mfma_k<9, 128><<<dim3(1, 36, 4), 256, 0, stream>>>(flo1, wkf2, bf2, cat, 64, 256, 192, 1);
  conv_mfma_k<9, 256><<<dim3(2, 36, 4), 256, 0, stream>>>(cat, wkcf, bcf, mf, 126, 128, 0, 1);
  copy_flow_k<<<dim3(72), 256, 0, stream>>>(flow, mf);
  conv_mfma_k<9, 128><<<dim3(4, 36, 4), 256, 0, stream>>>(mf, wkfh1, bfh1, fh1, 256, 256, 0, 1);
  convfh2_k<<<dim3(36), 256, 0, stream>>>(fh1, wfh2, bfh2, out_df);
  // 5. attention path (fp32, unchanged)
  pos_q_k<<<dim3(9216), 256, 0, stream>>>(fmap1, ws + F_SRCT, ws + F_Q);
  linear_k<false><<<dim3(1, 144), 256, 0, stream>>>(ws + F_Q, w_off, b_off, ws + F_OFF, 256, 64);
  linear_k<false><<<dim3(1, 144), 256, 0, stream>>>(ws + F_Q, w_aw, b_aw, ws + F_AW, 256, 32);
  linear_k<false><<<dim3(4, 144), 256, 0, stream>>>(ws + F_SRCT, w_val, b_val, ws + F_VAL, 256, 256);
  softmax4_k<<<dim3(288), 256, 0, stream>>>(ws + F_AW);
  deform_k<<<dim3(9216), 256, 0, stream>>>(ws + F_VAL, ws + F_OFF, ws + F_AW, ws + F_ATTN);
  linear_k<false><<<dim3(4, 144), 256, 0, stream>>>(ws + F_ATTN, w_out, b_out, ws + F_TMP, 256, 256);
  ln_add_k<<<dim3(9216), 256, 0, stream>>>(ws + F_TMP, ws + F_SRCT, ln1_g, ln1_b, ws + F_SRC1);
  linear_k<true><<<dim3(16, 144), 256, 0, stream>>>(ws + F_SRC1, w_ff1, b_ff1, ws + F_FF1, 256, 1024);
  linear_k<false><<<dim3(4, 144), 256, 0, stream>>>(ws + F_FF1, w_ff2, b_ff2, ws + F_FF2, 1024, 256);
  ln_add_k<<<dim3(9216), 256, 0, stream>>>(ws + F_FF2, ws + F_SRC1, ln2_g, ln2_b, out_src);

  (void)in_sizes; (void)n_in; (void)out_size; (void)ws_size;
}

// Round 4
// 454.440 us; speedup vs baseline: 3.4945x; 1.6361x over previous
//
#include <hip/hip_runtime.h>
#include <hip/hip_bf16.h>
#include <math.h>

#define HH 48
#define WW 48
#define HW 2304
#define BB 4
#define CC 256

typedef __hip_bfloat16 bf16;
typedef __attribute__((ext_vector_type(8))) short s8v;
typedef __attribute__((ext_vector_type(4))) float f4v;

__device__ inline float bf2f(short u) {
  unsigned v = ((unsigned)(unsigned short)u) << 16;
  return __builtin_bit_cast(float, v);
}

// ---------------- LDS tile transpose: fmap [B][C][HW] fp32 -> [B*HW][256] bf16 ----
__global__ __launch_bounds__(256) void transp_bf_k(const float* __restrict__ in,
                                                   bf16* __restrict__ out) {
  __shared__ float t[64][65];
  int p0 = blockIdx.x * 64, c0 = blockIdx.y * 64, b = blockIdx.z;
  const float* inb = in + ((size_t)b * CC + c0) * HW + p0;
#pragma unroll
  for (int i = 0; i < 16; ++i) {
    int idx = threadIdx.x + i * 256;
    int c = idx >> 6, p = idx & 63;
    t[c][p] = inb[(size_t)c * HW + p];
  }
  __syncthreads();
  bf16* ob = out + ((size_t)b * HW + p0) * 256 + c0;
#pragma unroll
  for (int i = 0; i < 16; ++i) {
    int idx = threadIdx.x + i * 256;
    int p = idx >> 6, c = idx & 63;
    ob[(size_t)p * 256 + c] = (bf16)t[c][p];
  }
}

// ---------------- fmap1 transpose + srcT fp32 + f1T bf16 + q=(src+pos) bf16 ----
__global__ __launch_bounds__(256) void pos_q_tile_k(const float* __restrict__ fmap1,
                                                    float* __restrict__ srcT,
                                                    bf16* __restrict__ f1t,
                                                    bf16* __restrict__ qb) {
  __shared__ float t[64][65];
  int p0 = blockIdx.x * 64, c0 = blockIdx.y * 64, b = blockIdx.z;
  const float* inb = fmap1 + ((size_t)b * CC + c0) * HW + p0;
#pragma unroll
  for (int i = 0; i < 16; ++i) {
    int idx = threadIdx.x + i * 256;
    int c = idx >> 6, p = idx & 63;
    t[c][p] = inb[(size_t)c * HW + p];
  }
  __syncthreads();
  const float TWO_PI = 6.283185307179586f;
#pragma unroll
  for (int i = 0; i < 16; ++i) {
    int idx = threadIdx.x + i * 256;
    int pl = idx >> 6, cl = idx & 63;
    int c = c0 + cl;
    int p = p0 + pl;
    int y = p / WW, x = p % WW;
    float s = t[cl][pl];
    int axis = c >> 7;
    int cc = c & 127;
    int m = cc >> 1;
    float coord = (axis ? ((float)x + 0.5f) : ((float)y + 0.5f)) * (TWO_PI / (48.f + 1e-6f));
    float tp = exp2f((float)m * (13.287712379549449f / 64.f));
    float a = coord / tp;
    float pv = (cc & 1) ? cosf(a) : sinf(a);
    size_t o = ((size_t)b * HW + p) * 256 + c;
    srcT[o] = s;
    f1t[o] = (bf16)s;
    qb[o] = (bf16)(s + pv);
  }
}

// ---------------- corr MFMA: corr[b][q][k] = (f1t[q].f2t[k])/16, bf16 out ----
__global__ __launch_bounds__(256) void corr_mfma_k(const bf16* __restrict__ f1t,
                                                   const bf16* __restrict__ f2t,
                                                   bf16* __restrict__ corr) {
  int b = blockIdx.z;
  int m0 = blockIdx.y * 64, n0 = blockIdx.x * 64;
  __shared__ short As[64][32];
  __shared__ short Bs[64][32];
  int tid = threadIdx.x;
  int srow = tid >> 2, sk8 = tid & 3;
  int dstk = (sk8 ^ (srow & 3)) * 8;
  int wave = tid >> 6, lane = tid & 63;
  int wm = (wave >> 1) * 32, wn = (wave & 1) * 32;
  int fl = lane & 15, fk8 = lane >> 4;
  f4v acc[2][2] = {};
  const bf16* arow = f1t + ((size_t)b * HW + m0 + srow) * 256;
  const bf16* brow = f2t + ((size_t)b * HW + n0 + srow) * 256;
#pragma unroll
  for (int c0 = 0; c0 < 256; c0 += 32) {
    uint4 av = *(const uint4*)(arow + c0 + sk8 * 8);
    uint4 bv = *(const uint4*)(brow + c0 + sk8 * 8);
    *(uint4*)&As[srow][dstk] = av;
    *(uint4*)&Bs[srow][dstk] = bv;
    __syncthreads();
    s8v af[2], bfr[2];
#pragma unroll
    for (int i = 0; i < 2; ++i) {
      int ar = wm + i * 16 + fl;
      af[i] = *(const s8v*)&As[ar][(fk8 ^ (ar & 3)) * 8];
      int br = wn + i * 16 + fl;
      bfr[i] = *(const s8v*)&Bs[br][(fk8 ^ (br & 3)) * 8];
    }
#pragma unroll
    for (int i = 0; i < 2; ++i)
#pragma unroll
      for (int j = 0; j < 2; ++j)
        acc[i][j] = __builtin_amdgcn_mfma_f32_16x16x32_bf16(af[i], bfr[j], acc[i][j], 0, 0, 0);
    __syncthreads();
  }
  bf16* outp = corr + ((size_t)b * HW + m0) * HW + n0;
#pragma unroll
  for (int j = 0; j < 2; ++j) {
    int o = wn + j * 16 + fl;
#pragma unroll
    for (int i = 0; i < 2; ++i)
#pragma unroll
      for (int r = 0; r < 4; ++r) {
        int m = wm + i * 16 + fk8 * 4 + r;
        outp[(size_t)m * HW + o] = (bf16)(acc[i][j][r] * 0.0625f);
      }
  }
}

// ---------------- 81-tap bilinear correlation lookup (bf16 corr) -> [n][96] bf16 ----
__global__ __launch_bounds__(256) void corr_lookup_k(const bf16* __restrict__ corr,
                                                     const float* __restrict__ flow,
                                                     bf16* __restrict__ cf) {
  int g = blockIdx.x * 256 + threadIdx.x;  // n*96 + t
  int t = g % 96;
  int n = g / 96;
  if (t >= 81) { cf[g] = (bf16)0.f; return; }
  int b = n / HW;
  int p = n % HW;
  int y = p / WW, x = p % WW;
  float fx = flow[((size_t)b * 2 + 0) * HW + p];
  float fy = flow[((size_t)b * 2 + 1) * HW + p];
  float px = (float)x + fx + (float)(t / 9 - 4);
  float py = (float)y + fy + (float)(t % 9 - 4);
  const bf16* row = corr + (size_t)n * HW;
  float x0f = floorf(px), y0f = floorf(py);
  int x0 = (int)x0f, y0 = (int)y0f;
  float wx = px - x0f, wy = py - y0f;
  float acc = 0.f;
  if ((unsigned)x0 < WW && (unsigned)y0 < HH) acc += (float)row[y0 * WW + x0] * (1.f - wx) * (1.f - wy);
  if ((unsigned)(x0 + 1) < WW && (unsigned)y0 < HH) acc += (float)row[y0 * WW + x0 + 1] * wx * (1.f - wy);
  if ((unsigned)x0 < WW && (unsigned)(y0 + 1) < HH) acc += (float)row[(y0 + 1) * WW + x0] * (1.f - wx) * wy;
  if ((unsigned)(x0 + 1) < WW && (unsigned)(y0 + 1) < HH) acc += (float)row[(y0 + 1) * WW + x0 + 1] * wx * wy;
  cf[g] = (bf16)acc;
}

// ---------------- weight convert: w[o][cin][t] fp32 -> wk[t][o][kp] bf16 (zero pad) ----
__global__ void wt_conv_k(const float* __restrict__ w, bf16* __restrict__ wk,
                          int Cout, int Cin, int KP, int KS) {
  int idx = blockIdx.x * 256 + threadIdx.x;
  int total = KS * KS * Cout * KP;
  if (idx >= total) return;
  int c = idx % KP;
  int o = (idx / KP) % Cout;
  int t = idx / (KP * Cout);
  float v = (c < Cin) ? w[((size_t)o * Cin + c) * (KS * KS) + t] : 0.f;
  wk[idx] = (bf16)v;
}

// ---------------- implicit-GEMM MFMA conv (3x3 pad1 or 1x1) ----------------
template <int TAPS, int KP>
__global__ __launch_bounds__(256) void conv_mfma_k(const bf16* __restrict__ in,
                                                   const bf16* __restrict__ wt,
                                                   const float* __restrict__ bias,
                                                   bf16* __restrict__ out, int Cout,
                                                   int OStride, int OOff, int relu) {
  int b = blockIdx.z;
  int m0 = blockIdx.y * 64;
  int n0 = blockIdx.x * 64;
  __shared__ short As[64][32];
  __shared__ short Bs[64][32];
  int tid = threadIdx.x;
  int srow = tid >> 2;
  int sk8 = tid & 3;
  int dstk = (sk8 ^ (srow & 3)) * 8;
  int q = m0 + srow;
  int y = q / WW, x = q - y * WW;
  int wave = tid >> 6;
  int lane = tid & 63;
  int wm = (wave >> 1) * 32;
  int wn = (wave & 1) * 32;
  int fl = lane & 15;
  int fk8 = lane >> 4;
  f4v acc[2][2] = {};
  const bf16* inb = in + (size_t)b * HW * KP;
  int wo = n0 + srow;
  bool wvalid = wo < Cout;
  for (int t = 0; t < TAPS; ++t) {
    int ky = (TAPS == 9) ? t / 3 : 0;
    int kx = (TAPS == 9) ? t - ky * 3 : 0;
    int yy = (TAPS == 9) ? (y + ky - 1) : y;
    int xx = (TAPS == 9) ? (x + kx - 1) : x;
    bool valid = ((unsigned)yy < (unsigned)HH) & ((unsigned)xx < (unsigned)WW);
    const bf16* srcrow = inb + (size_t)(yy * WW + xx) * KP;
    const bf16* wrow = wt + ((size_t)t * Cout + (wvalid ? wo : 0)) * KP;
#pragma unroll
    for (int c0 = 0; c0 < KP; c0 += 32) {
      uint4 av = {0u, 0u, 0u, 0u};
      if (valid) av = *(const uint4*)(srcrow + c0 + sk8 * 8);
      uint4 bv = {0u, 0u, 0u, 0u};
      if (wvalid) bv = *(const uint4*)(wrow + c0 + sk8 * 8);
      *(uint4*)&As[srow][dstk] = av;
      *(uint4*)&Bs[srow][dstk] = bv;
      __syncthreads();
      s8v af[2], bfr[2];
#pragma unroll
      for (int i = 0; i < 2; ++i) {
        int ar = wm + i * 16 + fl;
        af[i] = *(const s8v*)&As[ar][(fk8 ^ (ar & 3)) * 8];
        int br = wn + i * 16 + fl;
        bfr[i] = *(const s8v*)&Bs[br][(fk8 ^ (br & 3)) * 8];
      }
#pragma unroll
      for (int i = 0; i < 2; ++i)
#pragma unroll
        for (int j = 0; j < 2; ++j)
          acc[i][j] = __builtin_amdgcn_mfma_f32_16x16x32_bf16(af[i], bfr[j], acc[i][j], 0, 0, 0);
      __syncthreads();
    }
  }
  size_t outbase = ((size_t)b * HW + m0) * OStride + OOff;
#pragma unroll
  for (int j = 0; j < 2; ++j) {
    int o = n0 + wn + j * 16 + fl;
    if (o < Cout) {
      float bsv = bias[o];
#pragma unroll
      for (int i = 0; i < 2; ++i)
#pragma unroll
        for (int r = 0; r < 4; ++r) {
          int m = wm + i * 16 + fk8 * 4 + r;
          float v = acc[i][j][r] + bsv;
          if (relu) v = fmaxf(v, 0.f);
          out[outbase + (size_t)m * OStride + o] = (bf16)v;
        }
    }
  }
}

// ---------------- MFMA linear: in [N][KP] bf16, wt [O][KP] bf16 -> fp32 or bf16 ----
template <int KP, int RELU, int OUTB>
__global__ __launch_bounds__(256) void lin_mfma_k(const bf16* __restrict__ in,
                                                  const bf16* __restrict__ wt,
                                                  const float* __restrict__ bias,
                                                  float* __restrict__ outf,
                                                  bf16* __restrict__ outb, int O) {
  int m0 = blockIdx.y * 64;
  int n0 = blockIdx.x * 64;
  __shared__ short As[64][32];
  __shared__ short Bs[64][32];
  int tid = threadIdx.x;
  int srow = tid >> 2;
  int sk8 = tid & 3;
  int dstk = (sk8 ^ (srow & 3)) * 8;
  int wave = tid >> 6;
  int lane = tid & 63;
  int wm = (wave >> 1) * 32;
  int wn = (wave & 1) * 32;
  int fl = lane & 15;
  int fk8 = lane >> 4;
  f4v acc[2][2] = {};
  const bf16* arow = in + (size_t)(m0 + srow) * KP;
  int wo = n0 + srow;
  bool wvalid = wo < O;
  const bf16* wrow = wt + (size_t)(wvalid ? wo : 0) * KP;
  for (int c0 = 0; c0 < KP; c0 += 32) {
    uint4 av = *(const uint4*)(arow + c0 + sk8 * 8);
    uint4 bv = {0u, 0u, 0u, 0u};
    if (wvalid) bv = *(const uint4*)(wrow + c0 + sk8 * 8);
    *(uint4*)&As[srow][dstk] = av;
    *(uint4*)&Bs[srow][dstk] = bv;
    __syncthreads();
    s8v af[2], bfr[2];
#pragma unroll
    for (int i = 0; i < 2; ++i) {
      int ar = wm + i * 16 + fl;
      af[i] = *(const s8v*)&As[ar][(fk8 ^ (ar & 3)) * 8];
      int br = wn + i * 16 + fl;
      bfr[i] = *(const s8v*)&Bs[br][(fk8 ^ (br & 3)) * 8];
    }
#pragma unroll
    for (int i = 0; i < 2; ++i)
#pragma unroll
      for (int j = 0; j < 2; ++j)
        acc[i][j] = __builtin_amdgcn_mfma_f32_16x16x32_bf16(af[i], bfr[j], acc[i][j], 0, 0, 0);
    __syncthreads();
  }
#pragma unroll
  for (int j = 0; j < 2; ++j) {
    int o = n0 + wn + j * 16 + fl;
    if (o < O) {
      float bsv = bias[o];
#pragma unroll
      for (int i = 0; i < 2; ++i)
#pragma unroll
        for (int r = 0; r < 4; ++r) {
          int m = m0 + wm + i * 16 + fk8 * 4 + r;
          float v = acc[i][j][r] + bsv;
          if (RELU) v = fmaxf(v, 0.f);
          if (OUTB) outb[(size_t)m * O + o] = (bf16)v;
          else outf[(size_t)m * O + o] = v;
        }
    }
  }
}

// ---------------- 7x7 conv, Cin=2, Cout=128, LDS weights ----------------
__global__ __launch_bounds__(256) void conv7_k(const float* __restrict__ flow,
                                               const float* __restrict__ wf1,
                                               const float* __restrict__ bf1,
                                               bf16* __restrict__ out) {
  __shared__ float wl[49 * 2 * 128];
  int tid = threadIdx.x;
  for (int i = tid; i < 12544; i += 256) {
    int o_ = i & 127;
    int c_ = (i >> 7) & 1;
    int k_ = i >> 8;
    wl[i] = wf1[((size_t)o_ * 2 + c_) * 49 + k_];
  }
  __syncthreads();
  int pix = blockIdx.x * 2 + (tid >> 7);
  int o = tid & 127;
  int b = pix / HW;
  int p = pix % HW;
  int y = p / WW, x = p % WW;
  const float* f0 = flow + (size_t)b * 2 * HW;
  float acc = bf1[o];
  for (int ky = 0; ky < 7; ++ky) {
    int yy = y + ky - 3;
    if ((unsigned)yy >= (unsigned)HH) continue;
    for (int kx = 0; kx < 7; ++kx) {
      int xx = x + kx - 3;
      if ((unsigned)xx >= (unsigned)WW) continue;
      int sp = yy * WW + xx;
      float v0 = f0[sp];
      float v1 = f0[HW + sp];
      int k = ky * 7 + kx;
      acc += v0 * wl[(k * 2 + 0) * 128 + o] + v1 * wl[(k * 2 + 1) * 128 + o];
    }
  }
  out[(size_t)pix * 128 + o] = (bf16)fmaxf(acc, 0.f);
}

// ---------------- final 3x3 conv 256->2 ----------------
__global__ __launch_bounds__(256) void convfh2_k(const bf16* __restrict__ fh1,
                                                 const float* __restrict__ w,
                                                 const float* __restrict__ bias,
                                                 float* __restrict__ out) {
  int p = blockIdx.x * 256 + threadIdx.x;
  int b = p / HW;
  int q = p % HW;
  int y = q / WW, x = q % WW;
  float a0 = bias[0], a1 = bias[1];
  for (int ky = 0; ky < 3; ++ky) {
    int yy = y + ky - 1;
    if ((unsigned)yy >= (unsigned)HH) continue;
    for (int kx = 0; kx < 3; ++kx) {
      int xx = x + kx - 1;
      if ((unsigned)xx >= (unsigned)WW) continue;
      const s8v* row = (const s8v*)(fh1 + ((size_t)b * HW + yy * WW + xx) * 256);
      int t = ky * 3 + kx;
      for (int c8 = 0; c8 < 32; ++c8) {
        s8v v = row[c8];
#pragma unroll
        for (int j = 0; j < 8; ++j) {
          float fv = bf2f(v[j]);
          int c = c8 * 8 + j;
          a0 += fv * w[(size_t)(0 * 256 + c) * 9 + t];
          a1 += fv * w[(size_t)(1 * 256 + c) * 9 + t];
        }
      }
    }
  }
  out[(size_t)b * 2 * HW + q] = a0;
  out[((size_t)b * 2 + 1) * HW + q] = a1;
}

// ---------------- copy flow into mf cols 126,127 ----------------
__global__ void copy_flow_k(const float* __restrict__ flow, bf16* __restrict__ mf) {
  int g = blockIdx.x * 256 + threadIdx.x;
  int p = g % HW;
  int c = (g / HW) % 2;
  int b = g / (2 * HW);
  mf[((size_t)b * HW + p) * 128 + 126 + c] = (bf16)flow[g];
}

// ---------------- softmax over groups of 4 ----------------
__global__ void softmax4_k(float* aw) {
  int g = blockIdx.x * 256 + threadIdx.x;
  float* a = aw + (size_t)g * 4;
  float v0 = a[0], v1 = a[1], v2 = a[2], v3 = a[3];
  float m = fmaxf(fmaxf(v0, v1), fmaxf(v2, v3));
  float e0 = expf(v0 - m), e1 = expf(v1 - m), e2 = expf(v2 - m), e3 = expf(v3 - m);
  float inv = 1.f / (e0 + e1 + e2 + e3);
  a[0] = e0 * inv;
  a[1] = e1 * inv;
  a[2] = e2 * inv;
  a[3] = e3 * inv;
}

// ---------------- deformable sampling -> bf16 attn ----------------
__global__ __launch_bounds__(256) void deform_k(const float* __restrict__ val,
                                                const float* __restrict__ off,
                                                const float* __restrict__ aw,
                                                bf16* __restrict__ attn) {
  int g = blockIdx.x * 256 + threadIdx.x;
  int d = g & 31;
  int nh = g >> 5;
  int h = nh & 7;
  int n = nh >> 3;
  int b = n / HW;
  int p = n % HW;
  int y = p / WW, x = p % WW;
  const float* vb = val + (size_t)b * HW * 256 + h * 32 + d;
  float acc = 0.f;
#pragma unroll
  for (int pt = 0; pt < 4; ++pt) {
    float ox = off[(size_t)n * 64 + h * 8 + pt * 2 + 0];
    float oy = off[(size_t)n * 64 + h * 8 + pt * 2 + 1];
    float w = aw[(size_t)n * 32 + h * 4 + pt];
    float px = (float)x + ox, py = (float)y + oy;
    float x0f = floorf(px), y0f = floorf(py);
    int x0 = (int)x0f, y0 = (int)y0f;
    float wx = px - x0f, wy = py - y0f;
    float s = 0.f;
    if ((unsigned)x0 < WW && (unsigned)y0 < HH)
      s += vb[(size_t)(y0 * WW + x0) * 256] * (1.f - wx) * (1.f - wy);
    if ((unsigned)(x0 + 1) < WW && (unsigned)y0 < HH)
      s += vb[(size_t)(y0 * WW + x0 + 1) * 256] * wx * (1.f - wy);
    if ((unsigned)x0 < WW && (unsigned)(y0 + 1) < HH)
      s += vb[(size_t)((y0 + 1) * WW + x0) * 256] * (1.f - wx) * wy;
    if ((unsigned)(x0 + 1) < WW && (unsigned)(y0 + 1) < HH)
      s += vb[(size_t)((y0 + 1) * WW + x0 + 1) * 256] * wx * wy;
    acc += w * s;
  }
  attn[(size_t)n * 256 + h * 32 + d] = (bf16)acc;
}

// ---------------- fused residual add + LayerNorm over 256 (optional bf16 copy) ----
__global__ __launch_bounds__(256) void ln_add_k(const float* __restrict__ A,
                                                const float* __restrict__ Bv,
                                                const float* __restrict__ g,
                                                const float* __restrict__ be,
                                                float* __restrict__ out,
                                                bf16* __restrict__ outb) {
  int n = blockIdx.x;
  int c = threadIdx.x;
  float v = A[(size_t)n * 256 + c] + Bv[(size_t)n * 256 + c];
  float s1 = v, s2 = v * v;
#pragma unroll
  for (int o = 32; o > 0; o >>= 1) {
    s1 += __shfl_down(s1, o);
    s2 += __shfl_down(s2, o);
  }
  __shared__ float r1[4], r2[4], mv[2];
  int wid = c >> 6, lane = c & 63;
  if (lane == 0) {
    r1[wid] = s1;
    r2[wid] = s2;
  }
  __syncthreads();
  if (c == 0) {
    float a = r1[0] + r1[1] + r1[2] + r1[3];
    float q2 = r2[0] + r2[1] + r2[2] + r2[3];
    float mean = a * (1.f / 256.f);
    mv[0] = mean;
    mv[1] = q2 * (1.f / 256.f) - mean * mean;
  }
  __syncthreads();
  float mean = mv[0], var = mv[1];
  float r = (v - mean) * rsqrtf(var + 1e-5f) * g[c] + be[c];
  out[(size_t)n * 256 + c] = r;
  if (outb) outb[(size_t)n * 256 + c] = (bf16)r;
}

extern "C" void kernel_launch(void* const* d_in, const int* in_sizes, int n_in,
                              void* d_out, int out_size, void* d_ws, size_t ws_size,
                              hipStream_t stream) {
  const float* fmap1 = (const float*)d_in[0];
  const float* fmap2 = (const float*)d_in[1];
  const float* flow = (const float*)d_in[2];
  const float* wc1 = (const float*)d_in[3];
  const float* bc1 = (const float*)d_in[4];
  const float* wc2 = (const float*)d_in[5];
  const float* bc2 = (const float*)d_in[6];
  const float* wf1 = (const float*)d_in[7];
  const float* bf1 = (const float*)d_in[8];
  const float* wf2 = (const float*)d_in[9];
  const float* bf2 = (const float*)d_in[10];
  const float* wcf = (const float*)d_in[11];
  const float* bcf = (const float*)d_in[12];
  const float* wfh1 = (const float*)d_in[13];
  const float* bfh1 = (const float*)d_in[14];
  const float* wfh2 = (const float*)d_in[15];
  const float* bfh2 = (const float*)d_in[16];
  const float* w_off = (const float*)d_in[17];
  const float* b_off = (const float*)d_in[18];
  const float* w_aw = (const float*)d_in[19];
  const float* b_aw = (const float*)d_in[20];
  const float* w_val = (const float*)d_in[21];
  const float* b_val = (const float*)d_in[22];
  const float* w_out = (const float*)d_in[23];
  const float* b_out = (const float*)d_in[24];
  const float* ln1_g = (const float*)d_in[25];
  const float* ln1_b = (const float*)d_in[26];
  const float* w_ff1 = (const float*)d_in[27];
  const float* b_ff1 = (const float*)d_in[28];
  const float* w_ff2 = (const float*)d_in[29];
  const float* b_ff2 = (const float*)d_in[30];
  const float* ln2_g = (const float*)d_in[31];
  const float* ln2_b = (const float*)d_in[32];

  float* ws = (float*)d_ws;
  float* out_src = (float*)d_out;
  float* out_df = out_src + (size_t)BB * HW * CC;

  // ---- workspace layout (float offsets) ----
  // Phase A: corr bf16 [0, 10616832); f1t/f2t bf16 after it; cf, srcT, qb tail.
  const size_t F_CORR = 0;          // bf16 [B,HW,HW] = 10,616,832 fl
  const size_t F_F1T = 10616832;    // bf16 [n][256] = 1,179,648 fl
  const size_t F_F2T = 11796480;    // bf16 [n][256]
  const size_t F_CF = 12976128;     // bf16 [n][96] = 442,368 fl
  const size_t F_SRCT = 13418496;   // fp32 [n][256] = 2,359,296 fl (live till LN1)
  const size_t F_QBF = 15777792;    // bf16 [n][256] (dead after off/aw)
  // Phase B aliases in dead corr region:
  const size_t F_WK = 0;            // all bf16 weights (~903k fl)
  const size_t F_COR1 = 1000000;    // bf16 [n][256]
  const size_t F_CAT = 2200000;     // bf16 [n][256]
  const size_t F_FLO1 = 3400000;    // bf16 [n][128]
  const size_t F_MF = 4000000;      // bf16 [n][128]
  const size_t F_FH1 = 4600000;     // bf16 [n][256]
  const size_t F_OFF = 5800000;     // fp32 [n][64]
  const size_t F_AW = 6400000;      // fp32 [n][32]
  const size_t F_VAL = 6700000;     // fp32 [n][256]
  const size_t F_ATTN = 9100000;    // bf16 [n][256]
  const size_t F_TMP = 10616832;    // fp32 [n][256] (f1t/f2t dead after corr)
  const size_t F_SRC1 = 15777792;   // fp32 [n][256] (reuse qb region)
  const size_t F_SRC1B = 18137088;  // bf16 [n][256] -> high water 19,316,736 fl (77 MB)
  const size_t F_FF1 = 1000000;     // bf16 [n][1024] = 4,718,592 fl (convs dead)
  const size_t F_FF2 = 5800000;     // fp32 [n][256] (off/aw/val dead)

  bf16* corrb = (bf16*)(ws + F_CORR);
  bf16* f1t = (bf16*)(ws + F_F1T);
  bf16* f2t = (bf16*)(ws + F_F2T);
  bf16* cf = (bf16*)(ws + F_CF);
  bf16* qb = (bf16*)(ws + F_QBF);
  bf16* wkbase = (bf16*)(ws + F_WK);
  bf16* wk1 = wkbase + 0;            // [1][256][96]
  bf16* wk2 = wkbase + 24576;        // [9][192][256]
  bf16* wkf2 = wkbase + 466944;      // [9][64][128]
  bf16* wkcf = wkbase + 540672;      // [9][126][256]
  bf16* wkfh1 = wkbase + 830976;     // [9][256][128] end 1,125,888
  bf16* wl_off = wkbase + 1125888;   // [64][256]
  bf16* wl_aw = wkbase + 1142272;    // [32][256]
  bf16* wl_val = wkbase + 1150464;   // [256][256]
  bf16* wl_out = wkbase + 1216000;   // [256][256]
  bf16* wl_ff1 = wkbase + 1281536;   // [1024][256]
  bf16* wl_ff2 = wkbase + 1543680;   // [256][1024] end 1,805,824 bf16
  bf16* cor1 = (bf16*)(ws + F_COR1);
  bf16* cat = (bf16*)(ws + F_CAT);
  bf16* flo1 = (bf16*)(ws + F_FLO1);
  bf16* mf = (bf16*)(ws + F_MF);
  bf16* fh1 = (bf16*)(ws + F_FH1);
  bf16* attnb = (bf16*)(ws + F_ATTN);
  bf16* src1b = (bf16*)(ws + F_SRC1B);
  bf16* ff1b = (bf16*)(ws + F_FF1);

  // Phase A: transposes + corr + lookup
  transp_bf_k<<<dim3(36, 4, 4), 256, 0, stream>>>(fmap2, f2t);
  pos_q_tile_k<<<dim3(36, 4, 4), 256, 0, stream>>>(fmap1, ws + F_SRCT, f1t, qb);
  corr_mfma_k<<<dim3(36, 36, 4), 256, 0, stream>>>(f1t, f2t, corrb);
  corr_lookup_k<<<dim3(3456), 256, 0, stream>>>(corrb, flow, cf);
  // weights (corr region dead)
  wt_conv_k<<<dim3(96), 256, 0, stream>>>(wc1, wk1, 256, 81, 96, 1);
  wt_conv_k<<<dim3(1728), 256, 0, stream>>>(wc2, wk2, 192, 256, 256, 3);
  wt_conv_k<<<dim3(288), 256, 0, stream>>>(wf2, wkf2, 64, 128, 128, 3);
  wt_conv_k<<<dim3(1134), 256, 0, stream>>>(wcf, wkcf, 126, 256, 256, 3);
  wt_conv_k<<<dim3(1152), 256, 0, stream>>>(wfh1, wkfh1, 256, 128, 128, 3);
  wt_conv_k<<<dim3(64), 256, 0, stream>>>(w_off, wl_off, 64, 256, 256, 1);
  wt_conv_k<<<dim3(32), 256, 0, stream>>>(w_aw, wl_aw, 32, 256, 256, 1);
  wt_conv_k<<<dim3(256), 256, 0, stream>>>(w_val, wl_val, 256, 256, 256, 1);
  wt_conv_k<<<dim3(256), 256, 0, stream>>>(w_out, wl_out, 256, 256, 256, 1);
  wt_conv_k<<<dim3(1024), 256, 0, stream>>>(w_ff1, wl_ff1, 1024, 256, 256, 1);
  wt_conv_k<<<dim3(1024), 256, 0, stream>>>(w_ff2, wl_ff2, 256, 1024, 1024, 1);
  // motion encoder + flow head
  conv_mfma_k<1, 96><<<dim3(4, 36, 4), 256, 0, stream>>>(cf, wk1, bc1, cor1, 256, 256, 0, 1);
  conv_mfma_k<9, 256><<<dim3(3, 36, 4), 256, 0, stream>>>(cor1, wk2, bc2, cat, 192, 256, 0, 1);
  conv7_k<<<dim3(4608), 256, 0, stream>>>(flow, wf1, bf1, flo1);
  conv_mfma_k<9, 128><<<dim3(1, 36, 4), 256, 0, stream>>>(flo1, wkf2, bf2, cat, 64, 256, 192, 1);
  conv_mfma_k<9, 256><<<dim3(2, 36, 4), 256, 0, stream>>>(cat, wkcf, bcf, mf, 126, 128, 0, 1);
  copy_flow_k<<<dim3(72), 256, 0, stream>>>(flow, mf);
  conv_mfma_k<9, 128><<<dim3(4, 36, 4), 256, 0, stream>>>(mf, wkfh1, bfh1, fh1, 256, 256, 0, 1);
  convfh2_k<<<dim3(36), 256, 0, stream>>>(fh1, wfh2, bfh2, out_df);
  // attention path (bf16 MFMA linears)
  lin_mfma_k<256, 0, 0><<<dim3(1, 144), 256, 0, stream>>>(qb, wl_off, b_off, ws + F_OFF, nullptr, 64);
  lin_mfma_k<256, 0, 0><<<dim3(1, 144), 256, 0, stream>>>(qb, wl_aw, b_aw, ws + F_AW, nullptr, 32);
  lin_mfma_k<256, 0, 0><<<dim3(4, 144), 256, 0, stream>>>(f1t, wl_val, b_val, ws + F_VAL, nullptr, 256);
  softmax4_k<<<dim3(288), 256, 0, stream>>>(ws + F_AW);
  deform_k<<<dim3(9216), 256, 0, stream>>>(ws + F_VAL, ws + F_OFF, ws + F_AW, attnb);
  lin_mfma_k<256, 0, 0><<<dim3(4, 144), 256, 0, stream>>>(attnb, wl_out, b_out, ws + F_TMP, nullptr, 256);
  ln_add_k<<<dim3(9216), 256, 0, stream>>>(ws + F_TMP, ws + F_SRCT, ln1_g, ln1_b, ws + F_SRC1, src1b);
  lin_mfma_k<256, 1, 1><<<dim3(16, 144), 256, 0, stream>>>(src1b, wl_ff1, b_ff1, nullptr, ff1b, 1024);
  lin_mfma_k<1024, 0, 0><<<dim3(4, 144), 256, 0, stream>>>(ff1b, wl_ff2, b_ff2, ws + F_FF2, nullptr, 256);
  ln_add_k<<<dim3(9216), 256, 0, stream>>>(ws + F_FF2, ws + F_SRC1, ln2_g, ln2_b, out_src, nullptr);

  (void)in_sizes; (void)n_in; (void)out_size; (void)ws_size;
}

// Round 5
// 410.773 us; speedup vs baseline: 3.8660x; 1.1063x over previous
//
#include <hip/hip_runtime.h>
#include <hip/hip_bf16.h>
#include <math.h>

#define HH 48
#define WW 48
#define HW 2304
#define BB 4
#define CC 256

typedef __hip_bfloat16 bf16;
typedef __attribute__((ext_vector_type(8))) short s8v;
typedef __attribute__((ext_vector_type(4))) float f4v;

__device__ inline float bf2f(short u) {
  unsigned v = ((unsigned)(unsigned short)u) << 16;
  return __builtin_bit_cast(float, v);
}

// ---------------- LDS tile transpose: fmap [B][C][HW] fp32 -> [B*HW][256] bf16 ----
__global__ __launch_bounds__(256) void transp_bf_k(const float* __restrict__ in,
                                                   bf16* __restrict__ out) {
  __shared__ float t[64][65];
  int p0 = blockIdx.x * 64, c0 = blockIdx.y * 64, b = blockIdx.z;
  const float* inb = in + ((size_t)b * CC + c0) * HW + p0;
#pragma unroll
  for (int i = 0; i < 16; ++i) {
    int idx = threadIdx.x + i * 256;
    int c = idx >> 6, p = idx & 63;
    t[c][p] = inb[(size_t)c * HW + p];
  }
  __syncthreads();
  bf16* ob = out + ((size_t)b * HW + p0) * 256 + c0;
#pragma unroll
  for (int i = 0; i < 16; ++i) {
    int idx = threadIdx.x + i * 256;
    int p = idx >> 6, c = idx & 63;
    ob[(size_t)p * 256 + c] = (bf16)t[c][p];
  }
}

// ---------------- fmap1 transpose + srcT fp32 + f1T bf16 + q=(src+pos) bf16 ----
__global__ __launch_bounds__(256) void pos_q_tile_k(const float* __restrict__ fmap1,
                                                    float* __restrict__ srcT,
                                                    bf16* __restrict__ f1t,
                                                    bf16* __restrict__ qb) {
  __shared__ float t[64][65];
  int p0 = blockIdx.x * 64, c0 = blockIdx.y * 64, b = blockIdx.z;
  const float* inb = fmap1 + ((size_t)b * CC + c0) * HW + p0;
#pragma unroll
  for (int i = 0; i < 16; ++i) {
    int idx = threadIdx.x + i * 256;
    int c = idx >> 6, p = idx & 63;
    t[c][p] = inb[(size_t)c * HW + p];
  }
  __syncthreads();
  const float TWO_PI = 6.283185307179586f;
#pragma unroll
  for (int i = 0; i < 16; ++i) {
    int idx = threadIdx.x + i * 256;
    int pl = idx >> 6, cl = idx & 63;
    int c = c0 + cl;
    int p = p0 + pl;
    int y = p / WW, x = p % WW;
    float s = t[cl][pl];
    int axis = c >> 7;
    int cc = c & 127;
    int m = cc >> 1;
    float coord = (axis ? ((float)x + 0.5f) : ((float)y + 0.5f)) * (TWO_PI / (48.f + 1e-6f));
    float tp = exp2f((float)m * (13.287712379549449f / 64.f));
    float a = coord / tp;
    float pv = (cc & 1) ? cosf(a) : sinf(a);
    size_t o = ((size_t)b * HW + p) * 256 + c;
    srcT[o] = s;
    f1t[o] = (bf16)s;
    qb[o] = (bf16)(s + pv);
  }
}

// ---------------- corr MFMA: corr[b][q][k] = (f1t[q].f2t[k])/16, bf16 out ----
__global__ __launch_bounds__(256) void corr_mfma_k(const bf16* __restrict__ f1t,
                                                   const bf16* __restrict__ f2t,
                                                   bf16* __restrict__ corr) {
  int b = blockIdx.z;
  int m0 = blockIdx.y * 64, n0 = blockIdx.x * 64;
  __shared__ short As[64][32];
  __shared__ short Bs[64][32];
  int tid = threadIdx.x;
  int srow = tid >> 2, sk8 = tid & 3;
  int dstk = (sk8 ^ (srow & 3)) * 8;
  int wave = tid >> 6, lane = tid & 63;
  int wm = (wave >> 1) * 32, wn = (wave & 1) * 32;
  int fl = lane & 15, fk8 = lane >> 4;
  f4v acc[2][2] = {};
  const bf16* arow = f1t + ((size_t)b * HW + m0 + srow) * 256;
  const bf16* brow = f2t + ((size_t)b * HW + n0 + srow) * 256;
#pragma unroll
  for (int c0 = 0; c0 < 256; c0 += 32) {
    uint4 av = *(const uint4*)(arow + c0 + sk8 * 8);
    uint4 bv = *(const uint4*)(brow + c0 + sk8 * 8);
    *(uint4*)&As[srow][dstk] = av;
    *(uint4*)&Bs[srow][dstk] = bv;
    __syncthreads();
    s8v af[2], bfr[2];
#pragma unroll
    for (int i = 0; i < 2; ++i) {
      int ar = wm + i * 16 + fl;
      af[i] = *(const s8v*)&As[ar][(fk8 ^ (ar & 3)) * 8];
      int br = wn + i * 16 + fl;
      bfr[i] = *(const s8v*)&Bs[br][(fk8 ^ (br & 3)) * 8];
    }
#pragma unroll
    for (int i = 0; i < 2; ++i)
#pragma unroll
      for (int j = 0; j < 2; ++j)
        acc[i][j] = __builtin_amdgcn_mfma_f32_16x16x32_bf16(af[i], bfr[j], acc[i][j], 0, 0, 0);
    __syncthreads();
  }
  bf16* outp = corr + ((size_t)b * HW + m0) * HW + n0;
#pragma unroll
  for (int j = 0; j < 2; ++j) {
    int o = wn + j * 16 + fl;
#pragma unroll
    for (int i = 0; i < 2; ++i)
#pragma unroll
      for (int r = 0; r < 4; ++r) {
        int m = wm + i * 16 + fk8 * 4 + r;
        outp[(size_t)m * HW + o] = (bf16)(acc[i][j][r] * 0.0625f);
      }
  }
}

// ---------------- 81-tap bilinear correlation lookup (bf16 corr) -> [n][96] bf16 ----
__global__ __launch_bounds__(256) void corr_lookup_k(const bf16* __restrict__ corr,
                                                     const float* __restrict__ flow,
                                                     bf16* __restrict__ cf) {
  int g = blockIdx.x * 256 + threadIdx.x;  // n*96 + t
  int t = g % 96;
  int n = g / 96;
  if (t >= 81) { cf[g] = (bf16)0.f; return; }
  int b = n / HW;
  int p = n % HW;
  int y = p / WW, x = p % WW;
  float fx = flow[((size_t)b * 2 + 0) * HW + p];
  float fy = flow[((size_t)b * 2 + 1) * HW + p];
  float px = (float)x + fx + (float)(t / 9 - 4);
  float py = (float)y + fy + (float)(t % 9 - 4);
  const bf16* row = corr + (size_t)n * HW;
  float x0f = floorf(px), y0f = floorf(py);
  int x0 = (int)x0f, y0 = (int)y0f;
  float wx = px - x0f, wy = py - y0f;
  float acc = 0.f;
  if ((unsigned)x0 < WW && (unsigned)y0 < HH) acc += (float)row[y0 * WW + x0] * (1.f - wx) * (1.f - wy);
  if ((unsigned)(x0 + 1) < WW && (unsigned)y0 < HH) acc += (float)row[y0 * WW + x0 + 1] * wx * (1.f - wy);
  if ((unsigned)x0 < WW && (unsigned)(y0 + 1) < HH) acc += (float)row[(y0 + 1) * WW + x0] * (1.f - wx) * wy;
  if ((unsigned)(x0 + 1) < WW && (unsigned)(y0 + 1) < HH) acc += (float)row[(y0 + 1) * WW + x0 + 1] * wx * wy;
  cf[g] = (bf16)acc;
}

// ---------------- fused weight conversion: all 11 segments in one kernel ----------------
struct WtSegs {
  const float* src[11];
  unsigned dstOff[11];
  int Cout[11], Cin[11], KP[11], KS2[11];
  unsigned cum[12];
};

__global__ __launch_bounds__(256) void wt_all_k(WtSegs s, bf16* __restrict__ base) {
  unsigned idx = blockIdx.x * 256 + threadIdx.x;
  if (idx >= s.cum[11]) return;
  int seg = 0;
#pragma unroll
  for (int i = 1; i < 11; ++i)
    if (idx >= s.cum[i]) seg = i;
  unsigned r = idx - s.cum[seg];
  int KP = s.KP[seg], Cout = s.Cout[seg], Cin = s.Cin[seg], KS2 = s.KS2[seg];
  int c = r % KP;
  int o = (r / KP) % Cout;
  int t = r / (KP * Cout);
  float v = (c < Cin) ? s.src[seg][((size_t)o * Cin + c) * KS2 + t] : 0.f;
  base[s.dstOff[seg] + r] = (bf16)v;
}

// ---------------- implicit-GEMM MFMA conv (3x3 pad1 or 1x1) ----------------
template <int TAPS, int KP>
__global__ __launch_bounds__(256) void conv_mfma_k(const bf16* __restrict__ in,
                                                   const bf16* __restrict__ wt,
                                                   const float* __restrict__ bias,
                                                   bf16* __restrict__ out, int Cout,
                                                   int OStride, int OOff, int relu) {
  int b = blockIdx.z;
  int m0 = blockIdx.y * 64;
  int n0 = blockIdx.x * 64;
  __shared__ short As[64][32];
  __shared__ short Bs[64][32];
  int tid = threadIdx.x;
  int srow = tid >> 2;
  int sk8 = tid & 3;
  int dstk = (sk8 ^ (srow & 3)) * 8;
  int q = m0 + srow;
  int y = q / WW, x = q - y * WW;
  int wave = tid >> 6;
  int lane = tid & 63;
  int wm = (wave >> 1) * 32;
  int wn = (wave & 1) * 32;
  int fl = lane & 15;
  int fk8 = lane >> 4;
  f4v acc[2][2] = {};
  const bf16* inb = in + (size_t)b * HW * KP;
  int wo = n0 + srow;
  bool wvalid = wo < Cout;
  for (int t = 0; t < TAPS; ++t) {
    int ky = (TAPS == 9) ? t / 3 : 0;
    int kx = (TAPS == 9) ? t - ky * 3 : 0;
    int yy = (TAPS == 9) ? (y + ky - 1) : y;
    int xx = (TAPS == 9) ? (x + kx - 1) : x;
    bool valid = ((unsigned)yy < (unsigned)HH) & ((unsigned)xx < (unsigned)WW);
    const bf16* srcrow = inb + (size_t)(yy * WW + xx) * KP;
    const bf16* wrow = wt + ((size_t)t * Cout + (wvalid ? wo : 0)) * KP;
#pragma unroll
    for (int c0 = 0; c0 < KP; c0 += 32) {
      uint4 av = {0u, 0u, 0u, 0u};
      if (valid) av = *(const uint4*)(srcrow + c0 + sk8 * 8);
      uint4 bv = {0u, 0u, 0u, 0u};
      if (wvalid) bv = *(const uint4*)(wrow + c0 + sk8 * 8);
      *(uint4*)&As[srow][dstk] = av;
      *(uint4*)&Bs[srow][dstk] = bv;
      __syncthreads();
      s8v af[2], bfr[2];
#pragma unroll
      for (int i = 0; i < 2; ++i) {
        int ar = wm + i * 16 + fl;
        af[i] = *(const s8v*)&As[ar][(fk8 ^ (ar & 3)) * 8];
        int br = wn + i * 16 + fl;
        bfr[i] = *(const s8v*)&Bs[br][(fk8 ^ (br & 3)) * 8];
      }
#pragma unroll
      for (int i = 0; i < 2; ++i)
#pragma unroll
        for (int j = 0; j < 2; ++j)
          acc[i][j] = __builtin_amdgcn_mfma_f32_16x16x32_bf16(af[i], bfr[j], acc[i][j], 0, 0, 0);
      __syncthreads();
    }
  }
  size_t outbase = ((size_t)b * HW + m0) * OStride + OOff;
#pragma unroll
  for (int j = 0; j < 2; ++j) {
    int o = n0 + wn + j * 16 + fl;
    if (o < Cout) {
      float bsv = bias[o];
#pragma unroll
      for (int i = 0; i < 2; ++i)
#pragma unroll
        for (int r = 0; r < 4; ++r) {
          int m = wm + i * 16 + fk8 * 4 + r;
          float v = acc[i][j][r] + bsv;
          if (relu) v = fmaxf(v, 0.f);
          out[outbase + (size_t)m * OStride + o] = (bf16)v;
        }
    }
  }
}

// ---------------- MFMA linear: in [N][KP] bf16, wt [O][KP] bf16 -> fp32 or bf16 ----
template <int KP, int RELU, int OUTB>
__global__ __launch_bounds__(256) void lin_mfma_k(const bf16* __restrict__ in,
                                                  const bf16* __restrict__ wt,
                                                  const float* __restrict__ bias,
                                                  float* __restrict__ outf,
                                                  bf16* __restrict__ outb, int O) {
  int m0 = blockIdx.y * 64;
  int n0 = blockIdx.x * 64;
  __shared__ short As[64][32];
  __shared__ short Bs[64][32];
  int tid = threadIdx.x;
  int srow = tid >> 2;
  int sk8 = tid & 3;
  int dstk = (sk8 ^ (srow & 3)) * 8;
  int wave = tid >> 6;
  int lane = tid & 63;
  int wm = (wave >> 1) * 32;
  int wn = (wave & 1) * 32;
  int fl = lane & 15;
  int fk8 = lane >> 4;
  f4v acc[2][2] = {};
  const bf16* arow = in + (size_t)(m0 + srow) * KP;
  int wo = n0 + srow;
  bool wvalid = wo < O;
  const bf16* wrow = wt + (size_t)(wvalid ? wo : 0) * KP;
  for (int c0 = 0; c0 < KP; c0 += 32) {
    uint4 av = *(const uint4*)(arow + c0 + sk8 * 8);
    uint4 bv = {0u, 0u, 0u, 0u};
    if (wvalid) bv = *(const uint4*)(wrow + c0 + sk8 * 8);
    *(uint4*)&As[srow][dstk] = av;
    *(uint4*)&Bs[srow][dstk] = bv;
    __syncthreads();
    s8v af[2], bfr[2];
#pragma unroll
    for (int i = 0; i < 2; ++i) {
      int ar = wm + i * 16 + fl;
      af[i] = *(const s8v*)&As[ar][(fk8 ^ (ar & 3)) * 8];
      int br = wn + i * 16 + fl;
      bfr[i] = *(const s8v*)&Bs[br][(fk8 ^ (br & 3)) * 8];
    }
#pragma unroll
    for (int i = 0; i < 2; ++i)
#pragma unroll
      for (int j = 0; j < 2; ++j)
        acc[i][j] = __builtin_amdgcn_mfma_f32_16x16x32_bf16(af[i], bfr[j], acc[i][j], 0, 0, 0);
    __syncthreads();
  }
#pragma unroll
  for (int j = 0; j < 2; ++j) {
    int o = n0 + wn + j * 16 + fl;
    if (o < O) {
      float bsv = bias[o];
#pragma unroll
      for (int i = 0; i < 2; ++i)
#pragma unroll
        for (int r = 0; r < 4; ++r) {
          int m = m0 + wm + i * 16 + fk8 * 4 + r;
          float v = acc[i][j][r] + bsv;
          if (RELU) v = fmaxf(v, 0.f);
          if (OUTB) outb[(size_t)m * O + o] = (bf16)v;
          else outf[(size_t)m * O + o] = v;
        }
    }
  }
}

// ---------------- 7x7 conv, Cin=2, Cout=128, LDS weights, 36 px/block ----------------
// weights in LDS as wl[k*256 + o*2 + c] so the cin pair is one ds_read_b64.
__global__ __launch_bounds__(256) void conv7_k(const float* __restrict__ flow,
                                               const float* __restrict__ wf1,
                                               const float* __restrict__ bf1,
                                               bf16* __restrict__ out) {
  __shared__ float wl[12544];
  int tid = threadIdx.x;
#pragma unroll
  for (int i = tid; i < 12544; i += 256) {
    int k_ = i >> 8;
    int o_ = (i >> 1) & 127;
    int c_ = i & 1;
    wl[i] = wf1[((size_t)o_ * 2 + c_) * 49 + k_];
  }
  __syncthreads();
  int base = blockIdx.x * 36;  // 36 | 2304 so batch is uniform per block
  int b = base / HW;
  int pbase = base % HW;
  int o = tid & 127;
  int grp = tid >> 7;  // 0/1
  const float* f0 = flow + (size_t)b * 2 * HW;
  float bias = bf1[o];
  for (int it = 0; it < 18; ++it) {
    int p = pbase + it * 2 + grp;
    int y = p / WW, x = p % WW;
    float acc = bias;
#pragma unroll
    for (int ky = 0; ky < 7; ++ky) {
      int yy = y + ky - 3;
      if ((unsigned)yy >= (unsigned)HH) continue;
#pragma unroll
      for (int kx = 0; kx < 7; ++kx) {
        int xx = x + kx - 3;
        if ((unsigned)xx >= (unsigned)WW) continue;
        int sp = yy * WW + xx;
        float v0 = f0[sp];
        float v1 = f0[HW + sp];
        int k = ky * 7 + kx;
        float2 wp = *(const float2*)&wl[k * 256 + o * 2];
        acc += v0 * wp.x + v1 * wp.y;
      }
    }
    out[((size_t)b * HW + p) * 128 + o] = (bf16)fmaxf(acc, 0.f);
  }
}

// ---------------- final 3x3 conv 256->2, wave-per-pixel, LDS weights ----------------
// wl[(c*9+t)*2 + o2] = w[(o2*256+c)*9+t]
__global__ __launch_bounds__(256) void convfh2_k(const bf16* __restrict__ fh1,
                                                 const float* __restrict__ w,
                                                 const float* __restrict__ bias,
                                                 float* __restrict__ out) {
  __shared__ float wl[4608];
  int tid = threadIdx.x;
#pragma unroll
  for (int i = tid; i < 4608; i += 256) {
    int o2 = i & 1;
    int t = (i >> 1) % 9;
    int c = i / 18;
    wl[i] = w[((size_t)o2 * 256 + c) * 9 + t];
  }
  __syncthreads();
  int wave = tid >> 6, lane = tid & 63;
  int pix = blockIdx.x * 4 + wave;  // over B*HW
  int b = pix / HW;
  int q = pix % HW;
  int y = q / WW, x = q % WW;
  int c0 = lane * 4;
  float a0 = 0.f, a1 = 0.f;
#pragma unroll
  for (int ky = 0; ky < 3; ++ky) {
    int yy = y + ky - 1;
    if ((unsigned)yy >= (unsigned)HH) continue;
#pragma unroll
    for (int kx = 0; kx < 3; ++kx) {
      int xx = x + kx - 1;
      if ((unsigned)xx >= (unsigned)WW) continue;
      int t = ky * 3 + kx;
      const bf16* row = fh1 + ((size_t)b * HW + yy * WW + xx) * 256 + c0;
      ushort4 v = *(const ushort4*)row;
      unsigned short vv[4] = {v.x, v.y, v.z, v.w};
#pragma unroll
      for (int j = 0; j < 4; ++j) {
        float fv = bf2f((short)vv[j]);
        float2 wp = *(const float2*)&wl[((c0 + j) * 9 + t) * 2];
        a0 += fv * wp.x;
        a1 += fv * wp.y;
      }
    }
  }
#pragma unroll
  for (int offl = 32; offl > 0; offl >>= 1) {
    a0 += __shfl_xor(a0, offl);
    a1 += __shfl_xor(a1, offl);
  }
  if (lane == 0) {
    out[(size_t)b * 2 * HW + q] = a0 + bias[0];
    out[((size_t)b * 2 + 1) * HW + q] = a1 + bias[1];
  }
}

// ---------------- copy flow into mf cols 126,127 ----------------
__global__ void copy_flow_k(const float* __restrict__ flow, bf16* __restrict__ mf) {
  int g = blockIdx.x * 256 + threadIdx.x;
  int p = g % HW;
  int c = (g / HW) % 2;
  int b = g / (2 * HW);
  mf[((size_t)b * HW + p) * 128 + 126 + c] = (bf16)flow[g];
}

// ---------------- deformable sampling with inline softmax -> bf16 attn ----------------
__global__ __launch_bounds__(256) void deform_k(const float* __restrict__ val,
                                                const float* __restrict__ off,
                                                const float* __restrict__ aw,
                                                bf16* __restrict__ attn) {
  int g = blockIdx.x * 256 + threadIdx.x;
  int d = g & 31;
  int nh = g >> 5;
  int h = nh & 7;
  int n = nh >> 3;
  int b = n / HW;
  int p = n % HW;
  int y = p / WW, x = p % WW;
  // inline softmax over the 4 raw logits
  const float* ap = aw + (size_t)n * 32 + h * 4;
  float l0 = ap[0], l1 = ap[1], l2 = ap[2], l3 = ap[3];
  float mx = fmaxf(fmaxf(l0, l1), fmaxf(l2, l3));
  float e0 = expf(l0 - mx), e1 = expf(l1 - mx), e2 = expf(l2 - mx), e3 = expf(l3 - mx);
  float inv = 1.f / (e0 + e1 + e2 + e3);
  float wts[4] = {e0 * inv, e1 * inv, e2 * inv, e3 * inv};
  const float* vb = val + (size_t)b * HW * 256 + h * 32 + d;
  float acc = 0.f;
#pragma unroll
  for (int pt = 0; pt < 4; ++pt) {
    float ox = off[(size_t)n * 64 + h * 8 + pt * 2 + 0];
    float oy = off[(size_t)n * 64 + h * 8 + pt * 2 + 1];
    float w = wts[pt];
    float px = (float)x + ox, py = (float)y + oy;
    float x0f = floorf(px), y0f = floorf(py);
    int x0 = (int)x0f, y0 = (int)y0f;
    float wx = px - x0f, wy = py - y0f;
    float s = 0.f;
    if ((unsigned)x0 < WW && (unsigned)y0 < HH)
      s += vb[(size_t)(y0 * WW + x0) * 256] * (1.f - wx) * (1.f - wy);
    if ((unsigned)(x0 + 1) < WW && (unsigned)y0 < HH)
      s += vb[(size_t)(y0 * WW + x0 + 1) * 256] * wx * (1.f - wy);
    if ((unsigned)x0 < WW && (unsigned)(y0 + 1) < HH)
      s += vb[(size_t)((y0 + 1) * WW + x0) * 256] * (1.f - wx) * wy;
    if ((unsigned)(x0 + 1) < WW && (unsigned)(y0 + 1) < HH)
      s += vb[(size_t)((y0 + 1) * WW + x0 + 1) * 256] * wx * wy;
    acc += w * s;
  }
  attn[(size_t)n * 256 + h * 32 + d] = (bf16)acc;
}

// ---------------- fused residual add + LayerNorm over 256 (optional bf16 copy) ----
__global__ __launch_bounds__(256) void ln_add_k(const float* __restrict__ A,
                                                const float* __restrict__ Bv,
                                                const float* __restrict__ g,
                                                const float* __restrict__ be,
                                                float* __restrict__ out,
                                                bf16* __restrict__ outb) {
  int n = blockIdx.x;
  int c = threadIdx.x;
  float v = A[(size_t)n * 256 + c] + Bv[(size_t)n * 256 + c];
  float s1 = v, s2 = v * v;
#pragma unroll
  for (int o = 32; o > 0; o >>= 1) {
    s1 += __shfl_down(s1, o);
    s2 += __shfl_down(s2, o);
  }
  __shared__ float r1[4], r2[4], mv[2];
  int wid = c >> 6, lane = c & 63;
  if (lane == 0) {
    r1[wid] = s1;
    r2[wid] = s2;
  }
  __syncthreads();
  if (c == 0) {
    float a = r1[0] + r1[1] + r1[2] + r1[3];
    float q2 = r2[0] + r2[1] + r2[2] + r2[3];
    float mean = a * (1.f / 256.f);
    mv[0] = mean;
    mv[1] = q2 * (1.f / 256.f) - mean * mean;
  }
  __syncthreads();
  float mean = mv[0], var = mv[1];
  float r = (v - mean) * rsqrtf(var + 1e-5f) * g[c] + be[c];
  out[(size_t)n * 256 + c] = r;
  if (outb) outb[(size_t)n * 256 + c] = (bf16)r;
}

extern "C" void kernel_launch(void* const* d_in, const int* in_sizes, int n_in,
                              void* d_out, int out_size, void* d_ws, size_t ws_size,
                              hipStream_t stream) {
  const float* fmap1 = (const float*)d_in[0];
  const float* fmap2 = (const float*)d_in[1];
  const float* flow = (const float*)d_in[2];
  const float* wc1 = (const float*)d_in[3];
  const float* bc1 = (const float*)d_in[4];
  const float* wc2 = (const float*)d_in[5];
  const float* bc2 = (const float*)d_in[6];
  const float* wf1 = (const float*)d_in[7];
  const float* bf1 = (const float*)d_in[8];
  const float* wf2 = (const float*)d_in[9];
  const float* bf2 = (const float*)d_in[10];
  const float* wcf = (const float*)d_in[11];
  const float* bcf = (const float*)d_in[12];
  const float* wfh1 = (const float*)d_in[13];
  const float* bfh1 = (const float*)d_in[14];
  const float* wfh2 = (const float*)d_in[15];
  const float* bfh2 = (const float*)d_in[16];
  const float* w_off = (const float*)d_in[17];
  const float* b_off = (const float*)d_in[18];
  const float* w_aw = (const float*)d_in[19];
  const float* b_aw = (const float*)d_in[20];
  const float* w_val = (const float*)d_in[21];
  const float* b_val = (const float*)d_in[22];
  const float* w_out = (const float*)d_in[23];
  const float* b_out = (const float*)d_in[24];
  const float* ln1_g = (const float*)d_in[25];
  const float* ln1_b = (const float*)d_in[26];
  const float* w_ff1 = (const float*)d_in[27];
  const float* b_ff1 = (const float*)d_in[28];
  const float* w_ff2 = (const float*)d_in[29];
  const float* b_ff2 = (const float*)d_in[30];
  const float* ln2_g = (const float*)d_in[31];
  const float* ln2_b = (const float*)d_in[32];

  float* ws = (float*)d_ws;
  float* out_src = (float*)d_out;
  float* out_df = out_src + (size_t)BB * HW * CC;

  // ---- workspace layout (float offsets), identical to round 4 ----
  const size_t F_CORR = 0;
  const size_t F_F1T = 10616832;
  const size_t F_F2T = 11796480;
  const size_t F_CF = 12976128;
  const size_t F_SRCT = 13418496;
  const size_t F_QBF = 15777792;
  const size_t F_WK = 0;
  const size_t F_COR1 = 1000000;
  const size_t F_CAT = 2200000;
  const size_t F_FLO1 = 3400000;
  const size_t F_MF = 4000000;
  const size_t F_FH1 = 4600000;
  const size_t F_OFF = 5800000;
  const size_t F_AW = 6400000;
  const size_t F_VAL = 6700000;
  const size_t F_ATTN = 9100000;
  const size_t F_TMP = 10616832;
  const size_t F_SRC1 = 15777792;
  const size_t F_SRC1B = 18137088;
  const size_t F_FF1 = 1000000;
  const size_t F_FF2 = 5800000;

  bf16* corrb = (bf16*)(ws + F_CORR);
  bf16* f1t = (bf16*)(ws + F_F1T);
  bf16* f2t = (bf16*)(ws + F_F2T);
  bf16* cf = (bf16*)(ws + F_CF);
  bf16* qb = (bf16*)(ws + F_QBF);
  bf16* wkbase = (bf16*)(ws + F_WK);
  bf16* wk1 = wkbase + 0;
  bf16* wk2 = wkbase + 24576;
  bf16* wkf2 = wkbase + 466944;
  bf16* wkcf = wkbase + 540672;
  bf16* wkfh1 = wkbase + 830976;
  bf16* wl_off = wkbase + 1125888;
  bf16* wl_aw = wkbase + 1142272;
  bf16* wl_val = wkbase + 1150464;
  bf16* wl_out = wkbase + 1216000;
  bf16* wl_ff1 = wkbase + 1281536;
  bf16* wl_ff2 = wkbase + 1543680;
  bf16* cor1 = (bf16*)(ws + F_COR1);
  bf16* cat = (bf16*)(ws + F_CAT);
  bf16* flo1 = (bf16*)(ws + F_FLO1);
  bf16* mf = (bf16*)(ws + F_MF);
  bf16* fh1 = (bf16*)(ws + F_FH1);
  bf16* attnb = (bf16*)(ws + F_ATTN);
  bf16* src1b = (bf16*)(ws + F_SRC1B);
  bf16* ff1b = (bf16*)(ws + F_FF1);

  // Phase A: transposes + corr + lookup
  transp_bf_k<<<dim3(36, 4, 4), 256, 0, stream>>>(fmap2, f2t);
  pos_q_tile_k<<<dim3(36, 4, 4), 256, 0, stream>>>(fmap1, ws + F_SRCT, f1t, qb);
  corr_mfma_k<<<dim3(36, 36, 4), 256, 0, stream>>>(f1t, f2t, corrb);
  corr_lookup_k<<<dim3(3456), 256, 0, stream>>>(corrb, flow, cf);

  // fused weight conversion (corr region dead now)
  WtSegs segs;
  const float* srcs[11] = {wc1, wc2, wf2, wcf, wfh1, w_off, w_aw, w_val, w_out, w_ff1, w_ff2};
  unsigned offs[11] = {0, 24576, 466944, 540672, 830976, 1125888, 1142272, 1150464, 1216000, 1281536, 1543680};
  int couts[11] = {256, 192, 64, 126, 256, 64, 32, 256, 256, 1024, 256};
  int cins[11] = {81, 256, 128, 256, 128, 256, 256, 256, 256, 256, 1024};
  int kps[11] = {96, 256, 128, 256, 128, 256, 256, 256, 256, 256, 1024};
  int ks2[11] = {1, 9, 9, 9, 9, 1, 1, 1, 1, 1, 1};
  unsigned cum = 0;
  for (int i = 0; i < 11; ++i) {
    segs.src[i] = srcs[i];
    segs.dstOff[i] = offs[i];
    segs.Cout[i] = couts[i];
    segs.Cin[i] = cins[i];
    segs.KP[i] = kps[i];
    segs.KS2[i] = ks2[i];
    segs.cum[i] = cum;
    cum += (unsigned)(ks2[i] * couts[i] * kps[i]);
  }
  segs.cum[11] = cum;  // 1,805,824
  wt_all_k<<<dim3((cum + 255) / 256), 256, 0, stream>>>(segs, wkbase);

  // motion encoder + flow head
  conv_mfma_k<1, 96><<<dim3(4, 36, 4), 256, 0, stream>>>(cf, wk1, bc1, cor1, 256, 256, 0, 1);
  conv_mfma_k<9, 256><<<dim3(3, 36, 4), 256, 0, stream>>>(cor1, wk2, bc2, cat, 192, 256, 0, 1);
  conv7_k<<<dim3(256), 256, 0, stream>>>(flow, wf1, bf1, flo1);
  conv_mfma_k<9, 128><<<dim3(1, 36, 4), 256, 0, stream>>>(flo1, wkf2, bf2, cat, 64, 256, 192, 1);
  conv_mfma_k<9, 256><<<dim3(2, 36, 4), 256, 0, stream>>>(cat, wkcf, bcf, mf, 126, 128, 0, 1);
  copy_flow_k<<<dim3(72), 256, 0, stream>>>(flow, mf);
  conv_mfma_k<9, 128><<<dim3(4, 36, 4), 256, 0, stream>>>(mf, wkfh1, bfh1, fh1, 256, 256, 0, 1);
  convfh2_k<<<dim3(2304), 256, 0, stream>>>(fh1, wfh2, bfh2, out_df);

  // attention path (bf16 MFMA linears)
  lin_mfma_k<256, 0, 0><<<dim3(1, 144), 256, 0, stream>>>(qb, wl_off, b_off, ws + F_OFF, nullptr, 64);
  lin_mfma_k<256, 0, 0><<<dim3(1, 144), 256, 0, stream>>>(qb, wl_aw, b_aw, ws + F_AW, nullptr, 32);
  lin_mfma_k<256, 0, 0><<<dim3(4, 144), 256, 0, stream>>>(f1t, wl_val, b_val, ws + F_VAL, nullptr, 256);
  deform_k<<<dim3(9216), 256, 0, stream>>>(ws + F_VAL, ws + F_OFF, ws + F_AW, attnb);
  lin_mfma_k<256, 0, 0><<<dim3(4, 144), 256, 0, stream>>>(attnb, wl_out, b_out, ws + F_TMP, nullptr, 256);
  ln_add_k<<<dim3(9216), 256, 0, stream>>>(ws + F_TMP, ws + F_SRCT, ln1_g, ln1_b, ws + F_SRC1, src1b);
  lin_mfma_k<256, 1, 1><<<dim3(16, 144), 256, 0, stream>>>(src1b, wl_ff1, b_ff1, nullptr, ff1b, 1024);
  lin_mfma_k<1024, 0, 0><<<dim3(4, 144), 256, 0, stream>>>(ff1b, wl_ff2, b_ff2, ws + F_FF2, nullptr, 256);
  ln_add_k<<<dim3(9216), 256, 0, stream>>>(ws + F_FF2, ws + F_SRC1, ln2_g, ln2_b, out_src, nullptr);

  (void)in_sizes; (void)n_in; (void)out_size; (void)ws_size;
}

// Round 6
// 326.461 us; speedup vs baseline: 4.8644x; 1.2583x over previous
//
#include <hip/hip_runtime.h>
#include <hip/hip_bf16.h>
#include <math.h>

#define HH 48
#define WW 48
#define HW 2304
#define BB 4
#define CC 256

typedef __hip_bfloat16 bf16;
typedef __attribute__((ext_vector_type(8))) short s8v;
typedef __attribute__((ext_vector_type(4))) float f4v;

__device__ inline float bf2f(short u) {
  unsigned v = ((unsigned)(unsigned short)u) << 16;
  return __builtin_bit_cast(float, v);
}

// ---------------- LDS tile transpose: fmap [B][C][HW] fp32 -> [B*HW][256] bf16 ----
__global__ __launch_bounds__(256) void transp_bf_k(const float* __restrict__ in,
                                                   bf16* __restrict__ out) {
  __shared__ float t[64][65];
  int p0 = blockIdx.x * 64, c0 = blockIdx.y * 64, b = blockIdx.z;
  const float* inb = in + ((size_t)b * CC + c0) * HW + p0;
#pragma unroll
  for (int i = 0; i < 16; ++i) {
    int idx = threadIdx.x + i * 256;
    int c = idx >> 6, p = idx & 63;
    t[c][p] = inb[(size_t)c * HW + p];
  }
  __syncthreads();
  bf16* ob = out + ((size_t)b * HW + p0) * 256 + c0;
#pragma unroll
  for (int i = 0; i < 16; ++i) {
    int idx = threadIdx.x + i * 256;
    int p = idx >> 6, c = idx & 63;
    ob[(size_t)p * 256 + c] = (bf16)t[c][p];
  }
}

// ---------------- fmap1 transpose + srcT fp32 + f1T bf16 + q=(src+pos) bf16 ----
__global__ __launch_bounds__(256) void pos_q_tile_k(const float* __restrict__ fmap1,
                                                    float* __restrict__ srcT,
                                                    bf16* __restrict__ f1t,
                                                    bf16* __restrict__ qb) {
  __shared__ float t[64][65];
  int p0 = blockIdx.x * 64, c0 = blockIdx.y * 64, b = blockIdx.z;
  const float* inb = fmap1 + ((size_t)b * CC + c0) * HW + p0;
#pragma unroll
  for (int i = 0; i < 16; ++i) {
    int idx = threadIdx.x + i * 256;
    int c = idx >> 6, p = idx & 63;
    t[c][p] = inb[(size_t)c * HW + p];
  }
  __syncthreads();
  const float TWO_PI = 6.283185307179586f;
#pragma unroll
  for (int i = 0; i < 16; ++i) {
    int idx = threadIdx.x + i * 256;
    int pl = idx >> 6, cl = idx & 63;
    int c = c0 + cl;
    int p = p0 + pl;
    int y = p / WW, x = p % WW;
    float s = t[cl][pl];
    int axis = c >> 7;
    int cc = c & 127;
    int m = cc >> 1;
    float coord = (axis ? ((float)x + 0.5f) : ((float)y + 0.5f)) * (TWO_PI / (48.f + 1e-6f));
    float tp = exp2f((float)m * (13.287712379549449f / 64.f));
    float a = coord / tp;
    float pv = (cc & 1) ? cosf(a) : sinf(a);
    size_t o = ((size_t)b * HW + p) * 256 + c;
    srcT[o] = s;
    f1t[o] = (bf16)s;
    qb[o] = (bf16)(s + pv);
  }
}

// ---------------- corr MFMA: corr[b][q][k] = (f1t[q].f2t[k])/16, bf16 out ----
__global__ __launch_bounds__(256) void corr_mfma_k(const bf16* __restrict__ f1t,
                                                   const bf16* __restrict__ f2t,
                                                   bf16* __restrict__ corr) {
  int b = blockIdx.z;
  int m0 = blockIdx.y * 64, n0 = blockIdx.x * 64;
  __shared__ short As[64][32];
  __shared__ short Bs[64][32];
  int tid = threadIdx.x;
  int srow = tid >> 2, sk8 = tid & 3;
  int dstk = (sk8 ^ (srow & 3)) * 8;
  int wave = tid >> 6, lane = tid & 63;
  int wm = (wave >> 1) * 32, wn = (wave & 1) * 32;
  int fl = lane & 15, fk8 = lane >> 4;
  f4v acc[2][2] = {};
  const bf16* arow = f1t + ((size_t)b * HW + m0 + srow) * 256;
  const bf16* brow = f2t + ((size_t)b * HW + n0 + srow) * 256;
#pragma unroll
  for (int c0 = 0; c0 < 256; c0 += 32) {
    uint4 av = *(const uint4*)(arow + c0 + sk8 * 8);
    uint4 bv = *(const uint4*)(brow + c0 + sk8 * 8);
    *(uint4*)&As[srow][dstk] = av;
    *(uint4*)&Bs[srow][dstk] = bv;
    __syncthreads();
    s8v af[2], bfr[2];
#pragma unroll
    for (int i = 0; i < 2; ++i) {
      int ar = wm + i * 16 + fl;
      af[i] = *(const s8v*)&As[ar][(fk8 ^ (ar & 3)) * 8];
      int br = wn + i * 16 + fl;
      bfr[i] = *(const s8v*)&Bs[br][(fk8 ^ (br & 3)) * 8];
    }
#pragma unroll
    for (int i = 0; i < 2; ++i)
#pragma unroll
      for (int j = 0; j < 2; ++j)
        acc[i][j] = __builtin_amdgcn_mfma_f32_16x16x32_bf16(af[i], bfr[j], acc[i][j], 0, 0, 0);
    __syncthreads();
  }
  bf16* outp = corr + ((size_t)b * HW + m0) * HW + n0;
#pragma unroll
  for (int j = 0; j < 2; ++j) {
    int o = wn + j * 16 + fl;
#pragma unroll
    for (int i = 0; i < 2; ++i)
#pragma unroll
      for (int r = 0; r < 4; ++r) {
        int m = wm + i * 16 + fk8 * 4 + r;
        outp[(size_t)m * HW + o] = (bf16)(acc[i][j][r] * 0.0625f);
      }
  }
}

// ---------------- 81-tap bilinear correlation lookup (bf16 corr) -> [n][96] bf16 ----
__global__ __launch_bounds__(256) void corr_lookup_k(const bf16* __restrict__ corr,
                                                     const float* __restrict__ flow,
                                                     bf16* __restrict__ cf) {
  int g = blockIdx.x * 256 + threadIdx.x;  // n*96 + t
  int t = g % 96;
  int n = g / 96;
  if (t >= 81) { cf[g] = (bf16)0.f; return; }
  int b = n / HW;
  int p = n % HW;
  int y = p / WW, x = p % WW;
  float fx = flow[((size_t)b * 2 + 0) * HW + p];
  float fy = flow[((size_t)b * 2 + 1) * HW + p];
  float px = (float)x + fx + (float)(t / 9 - 4);
  float py = (float)y + fy + (float)(t % 9 - 4);
  const bf16* row = corr + (size_t)n * HW;
  float x0f = floorf(px), y0f = floorf(py);
  int x0 = (int)x0f, y0 = (int)y0f;
  float wx = px - x0f, wy = py - y0f;
  float acc = 0.f;
  if ((unsigned)x0 < WW && (unsigned)y0 < HH) acc += (float)row[y0 * WW + x0] * (1.f - wx) * (1.f - wy);
  if ((unsigned)(x0 + 1) < WW && (unsigned)y0 < HH) acc += (float)row[y0 * WW + x0 + 1] * wx * (1.f - wy);
  if ((unsigned)x0 < WW && (unsigned)(y0 + 1) < HH) acc += (float)row[(y0 + 1) * WW + x0] * (1.f - wx) * wy;
  if ((unsigned)(x0 + 1) < WW && (unsigned)(y0 + 1) < HH) acc += (float)row[(y0 + 1) * WW + x0 + 1] * wx * wy;
  cf[g] = (bf16)acc;
}

// ---------------- fused weight conversion: 12 segments (KS2==0 => conv7 repack) ----
struct WtSegs {
  const float* src[12];
  unsigned dstOff[12];
  int Cout[12], Cin[12], KP[12], KS2[12];
  unsigned cum[13];
};

__global__ __launch_bounds__(256) void wt_all_k(WtSegs s, bf16* __restrict__ base) {
  unsigned idx = blockIdx.x * 256 + threadIdx.x;
  if (idx >= s.cum[12]) return;
  int seg = 0;
#pragma unroll
  for (int i = 1; i < 12; ++i)
    if (idx >= s.cum[i]) seg = i;
  unsigned r = idx - s.cum[seg];
  int KP = s.KP[seg], Cout = s.Cout[seg], Cin = s.Cin[seg], KS2 = s.KS2[seg];
  int c = r % KP;
  int o = (r / KP) % Cout;
  int t = r / (KP * Cout);
  float v;
  if (KS2 == 0) {
    // conv7 linear weights: kp = cc*64 + tt; w[(o*2+cc)*49 + tt]
    int cc = c >> 6, tt = c & 63;
    v = (tt < 49) ? s.src[seg][((size_t)o * 2 + cc) * 49 + tt] : 0.f;
  } else {
    v = (c < Cin) ? s.src[seg][((size_t)o * Cin + c) * KS2 + t] : 0.f;
  }
  base[s.dstOff[seg] + r] = (bf16)v;
}

// ---------------- im2col for 7x7 pad3 conv on flow: col7[n][128] bf16 ----
// kp = cc*64 + tt (cc=cin 0/1, tt=tap 0..48, 49..63 zero)
__global__ __launch_bounds__(256) void im2col7_k(const float* __restrict__ flow,
                                                 bf16* __restrict__ col7) {
  int g = blockIdx.x * 256 + threadIdx.x;  // n*128 + kp
  int kp = g & 127;
  int n = g >> 7;
  int b = n / HW;
  int p = n % HW;
  int y = p / WW, x = p % WW;
  int cc = kp >> 6, tt = kp & 63;
  float v = 0.f;
  if (tt < 49) {
    int ky = tt / 7, kx = tt % 7;
    int yy = y + ky - 3, xx = x + kx - 3;
    if ((unsigned)yy < (unsigned)HH && (unsigned)xx < (unsigned)WW)
      v = flow[((size_t)b * 2 + cc) * HW + yy * WW + xx];
  }
  col7[g] = (bf16)v;
}

// ---------------- implicit-GEMM MFMA conv (3x3 pad1 or 1x1) ----------------
template <int TAPS, int KP>
__global__ __launch_bounds__(256) void conv_mfma_k(const bf16* __restrict__ in,
                                                   const bf16* __restrict__ wt,
                                                   const float* __restrict__ bias,
                                                   bf16* __restrict__ out, int Cout,
                                                   int OStride, int OOff, int relu) {
  int b = blockIdx.z;
  int m0 = blockIdx.y * 64;
  int n0 = blockIdx.x * 64;
  __shared__ short As[64][32];
  __shared__ short Bs[64][32];
  int tid = threadIdx.x;
  int srow = tid >> 2;
  int sk8 = tid & 3;
  int dstk = (sk8 ^ (srow & 3)) * 8;
  int q = m0 + srow;
  int y = q / WW, x = q - y * WW;
  int wave = tid >> 6;
  int lane = tid & 63;
  int wm = (wave >> 1) * 32;
  int wn = (wave & 1) * 32;
  int fl = lane & 15;
  int fk8 = lane >> 4;
  f4v acc[2][2] = {};
  const bf16* inb = in + (size_t)b * HW * KP;
  int wo = n0 + srow;
  bool wvalid = wo < Cout;
  for (int t = 0; t < TAPS; ++t) {
    int ky = (TAPS == 9) ? t / 3 : 0;
    int kx = (TAPS == 9) ? t - ky * 3 : 0;
    int yy = (TAPS == 9) ? (y + ky - 1) : y;
    int xx = (TAPS == 9) ? (x + kx - 1) : x;
    bool valid = ((unsigned)yy < (unsigned)HH) & ((unsigned)xx < (unsigned)WW);
    const bf16* srcrow = inb + (size_t)(yy * WW + xx) * KP;
    const bf16* wrow = wt + ((size_t)t * Cout + (wvalid ? wo : 0)) * KP;
#pragma unroll
    for (int c0 = 0; c0 < KP; c0 += 32) {
      uint4 av = {0u, 0u, 0u, 0u};
      if (valid) av = *(const uint4*)(srcrow + c0 + sk8 * 8);
      uint4 bv = {0u, 0u, 0u, 0u};
      if (wvalid) bv = *(const uint4*)(wrow + c0 + sk8 * 8);
      *(uint4*)&As[srow][dstk] = av;
      *(uint4*)&Bs[srow][dstk] = bv;
      __syncthreads();
      s8v af[2], bfr[2];
#pragma unroll
      for (int i = 0; i < 2; ++i) {
        int ar = wm + i * 16 + fl;
        af[i] = *(const s8v*)&As[ar][(fk8 ^ (ar & 3)) * 8];
        int br = wn + i * 16 + fl;
        bfr[i] = *(const s8v*)&Bs[br][(fk8 ^ (br & 3)) * 8];
      }
#pragma unroll
      for (int i = 0; i < 2; ++i)
#pragma unroll
        for (int j = 0; j < 2; ++j)
          acc[i][j] = __builtin_amdgcn_mfma_f32_16x16x32_bf16(af[i], bfr[j], acc[i][j], 0, 0, 0);
      __syncthreads();
    }
  }
  size_t outbase = ((size_t)b * HW + m0) * OStride + OOff;
#pragma unroll
  for (int j = 0; j < 2; ++j) {
    int o = n0 + wn + j * 16 + fl;
    if (o < Cout) {
      float bsv = bias[o];
#pragma unroll
      for (int i = 0; i < 2; ++i)
#pragma unroll
        for (int r = 0; r < 4; ++r) {
          int m = wm + i * 16 + fk8 * 4 + r;
          float v = acc[i][j][r] + bsv;
          if (relu) v = fmaxf(v, 0.f);
          out[outbase + (size_t)m * OStride + o] = (bf16)v;
        }
    }
  }
}

// ---------------- MFMA linear: in [N][KP] bf16, wt [O][KP] bf16 -> fp32 or bf16 ----
// bias2/split: for o >= split use bias2[o-split] (merged off+aw projection).
template <int KP, int RELU, int OUTB>
__global__ __launch_bounds__(256) void lin_mfma_k(const bf16* __restrict__ in,
                                                  const bf16* __restrict__ wt,
                                                  const float* __restrict__ bias,
                                                  const float* __restrict__ bias2,
                                                  int split,
                                                  float* __restrict__ outf,
                                                  bf16* __restrict__ outb, int O) {
  int m0 = blockIdx.y * 64;
  int n0 = blockIdx.x * 64;
  __shared__ short As[64][32];
  __shared__ short Bs[64][32];
  int tid = threadIdx.x;
  int srow = tid >> 2;
  int sk8 = tid & 3;
  int dstk = (sk8 ^ (srow & 3)) * 8;
  int wave = tid >> 6;
  int lane = tid & 63;
  int wm = (wave >> 1) * 32;
  int wn = (wave & 1) * 32;
  int fl = lane & 15;
  int fk8 = lane >> 4;
  f4v acc[2][2] = {};
  const bf16* arow = in + (size_t)(m0 + srow) * KP;
  int wo = n0 + srow;
  bool wvalid = wo < O;
  const bf16* wrow = wt + (size_t)(wvalid ? wo : 0) * KP;
  for (int c0 = 0; c0 < KP; c0 += 32) {
    uint4 av = *(const uint4*)(arow + c0 + sk8 * 8);
    uint4 bv = {0u, 0u, 0u, 0u};
    if (wvalid) bv = *(const uint4*)(wrow + c0 + sk8 * 8);
    *(uint4*)&As[srow][dstk] = av;
    *(uint4*)&Bs[srow][dstk] = bv;
    __syncthreads();
    s8v af[2], bfr[2];
#pragma unroll
    for (int i = 0; i < 2; ++i) {
      int ar = wm + i * 16 + fl;
      af[i] = *(const s8v*)&As[ar][(fk8 ^ (ar & 3)) * 8];
      int br = wn + i * 16 + fl;
      bfr[i] = *(const s8v*)&Bs[br][(fk8 ^ (br & 3)) * 8];
    }
#pragma unroll
    for (int i = 0; i < 2; ++i)
#pragma unroll
      for (int j = 0; j < 2; ++j)
        acc[i][j] = __builtin_amdgcn_mfma_f32_16x16x32_bf16(af[i], bfr[j], acc[i][j], 0, 0, 0);
    __syncthreads();
  }
#pragma unroll
  for (int j = 0; j < 2; ++j) {
    int o = n0 + wn + j * 16 + fl;
    if (o < O) {
      float bsv = (bias2 != nullptr && o >= split) ? bias2[o - split] : bias[o];
#pragma unroll
      for (int i = 0; i < 2; ++i)
#pragma unroll
        for (int r = 0; r < 4; ++r) {
          int m = m0 + wm + i * 16 + fk8 * 4 + r;
          float v = acc[i][j][r] + bsv;
          if (RELU) v = fmaxf(v, 0.f);
          if (OUTB) outb[(size_t)m * O + o] = (bf16)v;
          else outf[(size_t)m * O + o] = v;
        }
    }
  }
}

// ---------------- final 3x3 conv 256->2, wave-per-pixel, LDS weights ----------------
__global__ __launch_bounds__(256) void convfh2_k(const bf16* __restrict__ fh1,
                                                 const float* __restrict__ w,
                                                 const float* __restrict__ bias,
                                                 float* __restrict__ out) {
  __shared__ float wl[4608];
  int tid = threadIdx.x;
#pragma unroll
  for (int i = tid; i < 4608; i += 256) {
    int o2 = i & 1;
    int t = (i >> 1) % 9;
    int c = i / 18;
    wl[i] = w[((size_t)o2 * 256 + c) * 9 + t];
  }
  __syncthreads();
  int wave = tid >> 6, lane = tid & 63;
  int pix = blockIdx.x * 4 + wave;
  int b = pix / HW;
  int q = pix % HW;
  int y = q / WW, x = q % WW;
  int c0 = lane * 4;
  float a0 = 0.f, a1 = 0.f;
#pragma unroll
  for (int ky = 0; ky < 3; ++ky) {
    int yy = y + ky - 1;
    if ((unsigned)yy >= (unsigned)HH) continue;
#pragma unroll
    for (int kx = 0; kx < 3; ++kx) {
      int xx = x + kx - 1;
      if ((unsigned)xx >= (unsigned)WW) continue;
      int t = ky * 3 + kx;
      const bf16* row = fh1 + ((size_t)b * HW + yy * WW + xx) * 256 + c0;
      ushort4 v = *(const ushort4*)row;
      unsigned short vv[4] = {v.x, v.y, v.z, v.w};
#pragma unroll
      for (int j = 0; j < 4; ++j) {
        float fv = bf2f((short)vv[j]);
        float2 wp = *(const float2*)&wl[((c0 + j) * 9 + t) * 2];
        a0 += fv * wp.x;
        a1 += fv * wp.y;
      }
    }
  }
#pragma unroll
  for (int offl = 32; offl > 0; offl >>= 1) {
    a0 += __shfl_xor(a0, offl);
    a1 += __shfl_xor(a1, offl);
  }
  if (lane == 0) {
    out[(size_t)b * 2 * HW + q] = a0 + bias[0];
    out[((size_t)b * 2 + 1) * HW + q] = a1 + bias[1];
  }
}

// ---------------- copy flow into mf cols 126,127 ----------------
__global__ void copy_flow_k(const float* __restrict__ flow, bf16* __restrict__ mf) {
  int g = blockIdx.x * 256 + threadIdx.x;
  int p = g % HW;
  int c = (g / HW) % 2;
  int b = g / (2 * HW);
  mf[((size_t)b * HW + p) * 128 + 126 + c] = (bf16)flow[g];
}

// ---------------- deformable sampling with inline softmax; oa=[n][96] (off|aw) ----
__global__ __launch_bounds__(256) void deform_k(const float* __restrict__ val,
                                                const float* __restrict__ oa,
                                                bf16* __restrict__ attn) {
  int g = blockIdx.x * 256 + threadIdx.x;
  int d = g & 31;
  int nh = g >> 5;
  int h = nh & 7;
  int n = nh >> 3;
  int b = n / HW;
  int p = n % HW;
  int y = p / WW, x = p % WW;
  const float* ap = oa + (size_t)n * 96 + 64 + h * 4;
  float l0 = ap[0], l1 = ap[1], l2 = ap[2], l3 = ap[3];
  float mx = fmaxf(fmaxf(l0, l1), fmaxf(l2, l3));
  float e0 = expf(l0 - mx), e1 = expf(l1 - mx), e2 = expf(l2 - mx), e3 = expf(l3 - mx);
  float inv = 1.f / (e0 + e1 + e2 + e3);
  float wts[4] = {e0 * inv, e1 * inv, e2 * inv, e3 * inv};
  const float* offp = oa + (size_t)n * 96 + h * 8;
  const float* vb = val + (size_t)b * HW * 256 + h * 32 + d;
  float acc = 0.f;
#pragma unroll
  for (int pt = 0; pt < 4; ++pt) {
    float ox = offp[pt * 2 + 0];
    float oy = offp[pt * 2 + 1];
    float w = wts[pt];
    float px = (float)x + ox, py = (float)y + oy;
    float x0f = floorf(px), y0f = floorf(py);
    int x0 = (int)x0f, y0 = (int)y0f;
    float wx = px - x0f, wy = py - y0f;
    float s = 0.f;
    if ((unsigned)x0 < WW && (unsigned)y0 < HH)
      s += vb[(size_t)(y0 * WW + x0) * 256] * (1.f - wx) * (1.f - wy);
    if ((unsigned)(x0 + 1) < WW && (unsigned)y0 < HH)
      s += vb[(size_t)(y0 * WW + x0 + 1) * 256] * wx * (1.f - wy);
    if ((unsigned)x0 < WW && (unsigned)(y0 + 1) < HH)
      s += vb[(size_t)((y0 + 1) * WW + x0) * 256] * (1.f - wx) * wy;
    if ((unsigned)(x0 + 1) < WW && (unsigned)(y0 + 1) < HH)
      s += vb[(size_t)((y0 + 1) * WW + x0 + 1) * 256] * wx * wy;
    acc += w * s;
  }
  attn[(size_t)n * 256 + h * 32 + d] = (bf16)acc;
}

// ---------------- fused residual add + LayerNorm over 256 (optional bf16 copy) ----
__global__ __launch_bounds__(256) void ln_add_k(const float* __restrict__ A,
                                                const float* __restrict__ Bv,
                                                const float* __restrict__ g,
                                                const float* __restrict__ be,
                                                float* __restrict__ out,
                                                bf16* __restrict__ outb) {
  int n = blockIdx.x;
  int c = threadIdx.x;
  float v = A[(size_t)n * 256 + c] + Bv[(size_t)n * 256 + c];
  float s1 = v, s2 = v * v;
#pragma unroll
  for (int o = 32; o > 0; o >>= 1) {
    s1 += __shfl_down(s1, o);
    s2 += __shfl_down(s2, o);
  }
  __shared__ float r1[4], r2[4], mv[2];
  int wid = c >> 6, lane = c & 63;
  if (lane == 0) {
    r1[wid] = s1;
    r2[wid] = s2;
  }
  __syncthreads();
  if (c == 0) {
    float a = r1[0] + r1[1] + r1[2] + r1[3];
    float q2 = r2[0] + r2[1] + r2[2] + r2[3];
    float mean = a * (1.f / 256.f);
    mv[0] = mean;
    mv[1] = q2 * (1.f / 256.f) - mean * mean;
  }
  __syncthreads();
  float mean = mv[0], var = mv[1];
  float r = (v - mean) * rsqrtf(var + 1e-5f) * g[c] + be[c];
  out[(size_t)n * 256 + c] = r;
  if (outb) outb[(size_t)n * 256 + c] = (bf16)r;
}

extern "C" void kernel_launch(void* const* d_in, const int* in_sizes, int n_in,
                              void* d_out, int out_size, void* d_ws, size_t ws_size,
                              hipStream_t stream) {
  const float* fmap1 = (const float*)d_in[0];
  const float* fmap2 = (const float*)d_in[1];
  const float* flow = (const float*)d_in[2];
  const float* wc1 = (const float*)d_in[3];
  const float* bc1 = (const float*)d_in[4];
  const float* wc2 = (const float*)d_in[5];
  const float* bc2 = (const float*)d_in[6];
  const float* wf1 = (const float*)d_in[7];
  const float* bf1 = (const float*)d_in[8];
  const float* wf2 = (const float*)d_in[9];
  const float* bf2 = (const float*)d_in[10];
  const float* wcf = (const float*)d_in[11];
  const float* bcf = (const float*)d_in[12];
  const float* wfh1 = (const float*)d_in[13];
  const float* bfh1 = (const float*)d_in[14];
  const float* wfh2 = (const float*)d_in[15];
  const float* bfh2 = (const float*)d_in[16];
  const float* w_off = (const float*)d_in[17];
  const float* b_off = (const float*)d_in[18];
  const float* w_aw = (const float*)d_in[19];
  const float* b_aw = (const float*)d_in[20];
  const float* w_val = (const float*)d_in[21];
  const float* b_val = (const float*)d_in[22];
  const float* w_out = (const float*)d_in[23];
  const float* b_out = (const float*)d_in[24];
  const float* ln1_g = (const float*)d_in[25];
  const float* ln1_b = (const float*)d_in[26];
  const float* w_ff1 = (const float*)d_in[27];
  const float* b_ff1 = (const float*)d_in[28];
  const float* w_ff2 = (const float*)d_in[29];
  const float* b_ff2 = (const float*)d_in[30];
  const float* ln2_g = (const float*)d_in[31];
  const float* ln2_b = (const float*)d_in[32];

  float* ws = (float*)d_ws;
  float* out_src = (float*)d_out;
  float* out_df = out_src + (size_t)BB * HW * CC;

  // ---- workspace layout (float offsets) ----
  // Phase A: corr bf16 [0, 10,616,832); f1t/f2t/cf/srcT/qb in the tail.
  const size_t F_CORR = 0;
  const size_t F_F1T = 10616832;
  const size_t F_F2T = 11796480;
  const size_t F_CF = 12976128;
  const size_t F_SRCT = 13418496;
  const size_t F_QBF = 15777792;
  // Phase B aliases inside dead corr region (sequential liveness verified):
  const size_t F_WK = 0;            // bf16 weights: 1,822,208 bf16 = 911,104 fl
  const size_t F_COL7 = 950000;     // bf16 [n][128] = 589,824 fl, end 1,539,824
  const size_t F_COR1 = 1600000;    // bf16 [n][256] end 2,779,648
  const size_t F_CAT = 2800000;     // bf16 [n][256] end 3,979,648
  const size_t F_FLO1 = 4000000;    // bf16 [n][128] end 4,589,824
  const size_t F_MF = 4600000;      // bf16 [n][128] end 5,189,824
  const size_t F_FH1 = 5200000;     // bf16 [n][256] end 6,379,648 (dead before OA write)
  const size_t F_OA = 5200000;      // fp32 [n][96] = 884,736 fl, end 6,084,736
  const size_t F_VAL = 6100000;     // fp32 [n][256] = 2,359,296 fl, end 8,459,296
  const size_t F_ATTN = 8500000;    // bf16 [n][256] = 1,179,648 fl, end 9,679,648
  const size_t F_TMP = 10616832;    // fp32 [n][256] (f1t+f2t dead), end 12,976,128
  const size_t F_SRC1 = 15777792;   // fp32 [n][256] (qb dead)
  const size_t F_SRC1B = 18137088;  // bf16 [n][256], high water 19,316,736 fl
  const size_t F_FF1 = 1000000;     // bf16 [n][1024] = 4,718,592 fl, end 5,718,592
  const size_t F_FF2 = 5800000;     // fp32 [n][256], end 8,159,296

  bf16* corrb = (bf16*)(ws + F_CORR);
  bf16* f1t = (bf16*)(ws + F_F1T);
  bf16* f2t = (bf16*)(ws + F_F2T);
  bf16* cf = (bf16*)(ws + F_CF);
  bf16* qb = (bf16*)(ws + F_QBF);
  bf16* wkbase = (bf16*)(ws + F_WK);
  bf16* wk1 = wkbase + 0;            // [1][256][96]
  bf16* wk2 = wkbase + 24576;        // [9][192][256]
  bf16* wkf2 = wkbase + 466944;      // [9][64][128]
  bf16* wkcf = wkbase + 540672;      // [9][126][256]
  bf16* wkfh1 = wkbase + 830976;     // [9][256][128]
  bf16* wl_oa = wkbase + 1125888;    // [96][256] (off rows 0..63, aw rows 64..95)
  bf16* wl_val = wkbase + 1150464;   // [256][256]
  bf16* wl_out = wkbase + 1216000;   // [256][256]
  bf16* wl_ff1 = wkbase + 1281536;   // [1024][256]
  bf16* wl_ff2 = wkbase + 1543680;   // [256][1024]
  bf16* wk7 = wkbase + 1805824;      // [128][128] conv7 linear weights
  bf16* col7 = (bf16*)(ws + F_COL7);
  bf16* cor1 = (bf16*)(ws + F_COR1);
  bf16* cat = (bf16*)(ws + F_CAT);
  bf16* flo1 = (bf16*)(ws + F_FLO1);
  bf16* mf = (bf16*)(ws + F_MF);
  bf16* fh1 = (bf16*)(ws + F_FH1);
  bf16* attnb = (bf16*)(ws + F_ATTN);
  bf16* src1b = (bf16*)(ws + F_SRC1B);
  bf16* ff1b = (bf16*)(ws + F_FF1);

  // Phase A: transposes + corr + lookup
  transp_bf_k<<<dim3(36, 4, 4), 256, 0, stream>>>(fmap2, f2t);
  pos_q_tile_k<<<dim3(36, 4, 4), 256, 0, stream>>>(fmap1, ws + F_SRCT, f1t, qb);
  corr_mfma_k<<<dim3(36, 36, 4), 256, 0, stream>>>(f1t, f2t, corrb);
  corr_lookup_k<<<dim3(3456), 256, 0, stream>>>(corrb, flow, cf);

  // fused weight conversion (corr region dead now)
  WtSegs segs;
  const float* srcs[12] = {wc1, wc2, wf2, wcf, wfh1, w_off, w_aw, w_val, w_out, w_ff1, w_ff2, wf1};
  unsigned offs[12] = {0, 24576, 466944, 540672, 830976, 1125888, 1142272, 1150464, 1216000, 1281536, 1543680, 1805824};
  int couts[12] = {256, 192, 64, 126, 256, 64, 32, 256, 256, 1024, 256, 128};
  int cins[12] = {81, 256, 128, 256, 128, 256, 256, 256, 256, 256, 1024, 2};
  int kps[12] = {96, 256, 128, 256, 128, 256, 256, 256, 256, 256, 1024, 128};
  int ks2[12] = {1, 9, 9, 9, 9, 1, 1, 1, 1, 1, 1, 0};  // 0 = conv7 sentinel
  unsigned cum = 0;
  for (int i = 0; i < 12; ++i) {
    segs.src[i] = srcs[i];
    segs.dstOff[i] = offs[i];
    segs.Cout[i] = couts[i];
    segs.Cin[i] = cins[i];
    segs.KP[i] = kps[i];
    segs.KS2[i] = ks2[i];
    segs.cum[i] = cum;
    cum += (unsigned)((ks2[i] ? ks2[i] : 1) * couts[i] * kps[i]);
  }
  segs.cum[12] = cum;  // 1,822,208
  wt_all_k<<<dim3((cum + 255) / 256), 256, 0, stream>>>(segs, wkbase);

  // motion encoder + flow head
  conv_mfma_k<1, 96><<<dim3(4, 36, 4), 256, 0, stream>>>(cf, wk1, bc1, cor1, 256, 256, 0, 1);
  conv_mfma_k<9, 256><<<dim3(3, 36, 4), 256, 0, stream>>>(cor1, wk2, bc2, cat, 192, 256, 0, 1);
  im2col7_k<<<dim3(4608), 256, 0, stream>>>(flow, col7);
  lin_mfma_k<128, 1, 1><<<dim3(2, 144), 256, 0, stream>>>(col7, wk7, bf1, nullptr, 1 << 30, nullptr, flo1, 128);
  conv_mfma_k<9, 128><<<dim3(1, 36, 4), 256, 0, stream>>>(flo1, wkf2, bf2, cat, 64, 256, 192, 1);
  conv_mfma_k<9, 256><<<dim3(2, 36, 4), 256, 0, stream>>>(cat, wkcf, bcf, mf, 126, 128, 0, 1);
  copy_flow_k<<<dim3(72), 256, 0, stream>>>(flow, mf);
  conv_mfma_k<9, 128><<<dim3(4, 36, 4), 256, 0, stream>>>(mf, wkfh1, bfh1, fh1, 256, 256, 0, 1);
  convfh2_k<<<dim3(2304), 256, 0, stream>>>(fh1, wfh2, bfh2, out_df);

  // attention path
  lin_mfma_k<256, 0, 0><<<dim3(2, 144), 256, 0, stream>>>(qb, wl_oa, b_off, b_aw, 64, ws + F_OA, nullptr, 96);
  lin_mfma_k<256, 0, 0><<<dim3(4, 144), 256, 0, stream>>>(f1t, wl_val, b_val, nullptr, 1 << 30, ws + F_VAL, nullptr, 256);
  deform_k<<<dim3(9216), 256, 0, stream>>>(ws + F_VAL, ws + F_OA, attnb);
  lin_mfma_k<256, 0, 0><<<dim3(4, 144), 256, 0, stream>>>(attnb, wl_out, b_out, nullptr, 1 << 30, ws + F_TMP, nullptr, 256);
  ln_add_k<<<dim3(9216), 256, 0, stream>>>(ws + F_TMP, ws + F_SRCT, ln1_g, ln1_b, ws + F_SRC1, src1b);
  lin_mfma_k<256, 1, 1><<<dim3(16, 144), 256, 0, stream>>>(src1b, wl_ff1, b_ff1, nullptr, 1 << 30, nullptr, ff1b, 1024);
  lin_mfma_k<1024, 0, 0><<<dim3(4, 144), 256, 0, stream>>>(ff1b, wl_ff2, b_ff2, nullptr, 1 << 30, ws + F_FF2, nullptr, 256);
  ln_add_k<<<dim3(9216), 256, 0, stream>>>(ws + F_FF2, ws + F_SRC1, ln2_g, ln2_b, out_src, nullptr);

  (void)in_sizes; (void)n_in; (void)out_size; (void)ws_size;
}